// Round 5
// baseline (1140.543 us; speedup 1.0000x reference)
//
#include <hip/hip_runtime.h>
#include <math.h>

#define N_NODES 50000
#define E_EDGES 1600000
#define F_IN    2000
#define D       20
#define NCOL    160   // 2 edge types * [q s k v] * 20  (col order: q,s,k,v per edge type)
#define KPAD    2016  // 63 * 32

#define INV_SQRT_D 0.22360679774997896f

typedef __bf16 bf16x8 __attribute__((ext_vector_type(8)));
typedef __bf16 bf16x4 __attribute__((ext_vector_type(4)));
typedef float  f32x4  __attribute__((ext_vector_type(4)));

// ---------------- pack weights + zero accumulators --------------------------------------
// Column order within each 80-col edge-type block: q(0-19) s(20-39) k(40-59) v(60-79)
// -> attention gathers k+v as one 80B 16B-aligned chunk.
__global__ void pack_kernel(
    const float* __restrict__ W0q, const float* __restrict__ W0k,
    const float* __restrict__ W0v, const float* __restrict__ W0s,
    const float* __restrict__ b0q, const float* __restrict__ b0k,
    const float* __restrict__ b0v, const float* __restrict__ b0s,
    const float* __restrict__ Wq,  const float* __restrict__ Wk,
    const float* __restrict__ Wv,  const float* __restrict__ Ws_,
    const float* __restrict__ bq,  const float* __restrict__ bk,
    const float* __restrict__ bv,  const float* __restrict__ bs_,
    __bf16* __restrict__ B0, float* __restrict__ bias0,
    float* __restrict__ WL, float* __restrict__ biasL,
    float* __restrict__ bn, int* __restrict__ deg)
{
  long idx = (long)blockIdx.x * blockDim.x + threadIdx.x;
  if (idx < (long)NCOL*KPAD) {              // B0T: [160][2016] bf16
    int col = (int)(idx / KPAD), k = (int)(idx % KPAD);
    int et = col / 80, r = col % 80, mat = r / 20, d = r % 20;
    const float* w = (mat==0)?W0q:(mat==1)?W0s:(mat==2)?W0k:W0v;
    float v = (k < F_IN) ? w[((size_t)et*F_IN + k)*D + d] : 0.f;
    B0[idx] = (__bf16)v;
    return;
  }
  idx -= (long)NCOL*KPAD;
  if (idx < 160) {                          // bias0
    int col = (int)idx;
    int et = col / 80, r = col % 80, mat = r / 20, d = r % 20;
    const float* b = (mat==0)?b0q:(mat==1)?b0s:(mat==2)?b0k:b0v;
    bias0[col] = b[et*D + d];
    return;
  }
  idx -= 160;
  if (idx < 9600) {                         // WL: 3 x [20][160]
    int l = (int)(idx / 3200), rem = (int)(idx % 3200);
    int k = rem / NCOL, col = rem % NCOL;
    int et = col / 80, r = col % 80, mat = r / 20, d = r % 20;
    const float* w = (mat==0)?Wq:(mat==1)?Ws_:(mat==2)?Wk:Wv;
    WL[idx] = w[(((size_t)l*2 + et)*D + k)*D + d];
    return;
  }
  idx -= 9600;
  if (idx < 480) {                          // biasL: 3 x [160]
    int l = (int)(idx / NCOL), col = (int)(idx % NCOL);
    int et = col / 80, r = col % 80, mat = r / 20, d = r % 20;
    const float* b = (mat==0)?bq:(mat==1)?bs_:(mat==2)?bk:bv;
    biasL[idx] = b[(l*2 + et)*D + d];
    return;
  }
  idx -= 480;
  if (idx < 320) { bn[idx] = 0.f; return; } // BN accumulators, 4 layers x 80
  idx -= 320;
  if (idx < 2*N_NODES) { deg[idx] = 0; return; }
}

// ---------------- CSR build (indices static across layers -> build once per call) -------
__global__ void hist_kernel(const int* __restrict__ same, const int* __restrict__ diff,
                            int* __restrict__ deg)
{
  long i = (long)blockIdx.x * blockDim.x + threadIdx.x;
  if (i >= 2L*E_EDGES) return;
  int et = (i >= E_EDGES) ? 1 : 0;
  long e = i - (long)et*E_EDGES;
  const int* ix = et ? diff : same;
  int dst = ix[E_EDGES + e];
  atomicAdd(&deg[(size_t)et*N_NODES + dst], 1);
}

__global__ void scan_kernel(const int* __restrict__ deg,
                            int* __restrict__ rowptr0, int* __restrict__ rowptr1,
                            int* __restrict__ next0, int* __restrict__ next1)
{
  const int et = blockIdx.x;
  const int* dg = deg + (size_t)et*N_NODES;
  int* rp = et ? rowptr1 : rowptr0;
  int* np = et ? next1 : next0;
  __shared__ int part[1024];
  const int t = threadIdx.x;
  const int per = (N_NODES + 1023) / 1024;  // 49
  const int b = t * per;
  const int e = (b + per < N_NODES) ? (b + per) : N_NODES;
  int s = 0;
  for (int i = b; i < e; i++) s += dg[i];
  part[t] = s;
  __syncthreads();
  for (int o = 1; o < 1024; o <<= 1) {
    int v = (t >= o) ? part[t-o] : 0;
    __syncthreads();
    part[t] += v;
    __syncthreads();
  }
  int run = (t == 0) ? 0 : part[t-1];
  for (int i = b; i < e; i++) {
    rp[i] = run; np[i] = run;
    run += dg[i];
  }
  if (t == 0) rp[N_NODES] = part[1023];
}

// XCD-partitioned scatter: partition p (= blockIdx&7, default round-robin XCD mapping)
// owns dst range [p*6250,(p+1)*6250) so each adj cache line is dirtied from one XCD.
#define SC_EPT 16
#define SC_CHUNK (256*SC_EPT)
__global__ void scatter_kernel(const int* __restrict__ same, const int* __restrict__ diff,
                               int* __restrict__ next0, int* __restrict__ next1,
                               int* __restrict__ adj0, int* __restrict__ adj1)
{
  const int part  = blockIdx.x & 7;
  const int chunk = blockIdx.x >> 3;
  const int lo = part * (N_NODES/8);
  const int hi = lo + (N_NODES/8);
  const long i0 = (long)chunk * SC_CHUNK + threadIdx.x;
#pragma unroll
  for (int it = 0; it < SC_EPT; ++it) {
    long i = i0 + (long)it*256;
    if (i >= 2L*E_EDGES) break;
    int et = (i >= E_EDGES) ? 1 : 0;
    long e = i - (long)et*E_EDGES;
    const int* ix = et ? diff : same;
    int dst = ix[E_EDGES + e];
    if (dst >= lo && dst < hi) {
      int src = ix[e];
      int* np  = et ? next1 : next0;
      int* adj = et ? adj1  : adj0;
      int pos = atomicAdd(&np[dst], 1);
      adj[pos] = src;
    }
  }
}

// ---------------- layer-0 MFMA GEMM: [50000,2000]fp32 -> bf16 @ [2016,160]bf16 ----------
__launch_bounds__(512)
__global__ void gemm0_mfma(const float* __restrict__ A,
                           const __bf16* __restrict__ Bt,
                           const float* __restrict__ bias,
                           __bf16* __restrict__ C)
{
  __shared__ __bf16 as[128*32];
  const int t    = threadIdx.x;
  const int lane = t & 63;
  const int wid  = t >> 6;
  const int wr   = wid >> 1;        // 0..3 -> rows wr*32
  const int wc   = wid & 1;         // 0..1 -> cols wc*80
  const int rb0  = blockIdx.x * 128;

  const int srow = t >> 2;          // staging: row 0..127
  const int skc  = (t & 3) * 8;     // k chunk of 8
  const int arow = rb0 + srow;
  const float* aptr = A + (size_t)arow * F_IN;

  const int lrow = lane & 15;       // frag row/col within 16
  const int lkb  = (lane >> 4) * 8; // k sub-block

  f32x4 acc[2][5];
#pragma unroll
  for (int i = 0; i < 2; i++)
#pragma unroll
    for (int j = 0; j < 5; j++) acc[i][j] = (f32x4){0.f,0.f,0.f,0.f};

  float4 p0, p1;
  auto loadA = [&](int k0) {
    int k = k0 + skc;
    if (arow < N_NODES) {
      if (k + 8 <= F_IN) {
        p0 = *(const float4*)(aptr + k);
        p1 = *(const float4*)(aptr + k + 4);
      } else {
        float tmp[8];
#pragma unroll
        for (int i = 0; i < 8; i++) tmp[i] = (k + i < F_IN) ? aptr[k + i] : 0.f;
        p0 = make_float4(tmp[0],tmp[1],tmp[2],tmp[3]);
        p1 = make_float4(tmp[4],tmp[5],tmp[6],tmp[7]);
      }
    } else {
      p0 = make_float4(0,0,0,0); p1 = p0;
    }
  };

  loadA(0);
  for (int s = 0; s < 63; s++) {
    bf16x8 h;
    h[0]=(__bf16)p0.x; h[1]=(__bf16)p0.y; h[2]=(__bf16)p0.z; h[3]=(__bf16)p0.w;
    h[4]=(__bf16)p1.x; h[5]=(__bf16)p1.y; h[6]=(__bf16)p1.z; h[7]=(__bf16)p1.w;
    *(bf16x8*)&as[srow*32 + skc] = h;
    __syncthreads();
    if (s + 1 < 63) loadA((s + 1) * 32);

    bf16x8 af[2];
#pragma unroll
    for (int rf = 0; rf < 2; rf++)
      af[rf] = *(bf16x8*)&as[(wr*32 + rf*16 + lrow)*32 + lkb];
    bf16x8 bfr[5];
#pragma unroll
    for (int cf = 0; cf < 5; cf++)
      bfr[cf] = *(const bf16x8*)(Bt + (size_t)(wc*80 + cf*16 + lrow)*KPAD + s*32 + lkb);
#pragma unroll
    for (int rf = 0; rf < 2; rf++)
#pragma unroll
      for (int cf = 0; cf < 5; cf++)
        acc[rf][cf] = __builtin_amdgcn_mfma_f32_16x16x32_bf16(af[rf], bfr[cf], acc[rf][cf], 0, 0, 0);
    __syncthreads();
  }

  // epilogue: C/D layout col=lane&15, row=(lane>>4)*4 + j ; C is bf16 [N][160]
#pragma unroll
  for (int rf = 0; rf < 2; rf++) {
#pragma unroll
    for (int cf = 0; cf < 5; cf++) {
      int col = wc*80 + cf*16 + lrow;
      float bv = bias[col];
#pragma unroll
      for (int j = 0; j < 4; j++) {
        int r = rb0 + wr*32 + rf*16 + (lane >> 4)*4 + j;
        if (r < N_NODES) C[(size_t)r*NCOL + col] = (__bf16)(acc[rf][cf][j] + bv);
      }
    }
  }
}

// ---------------- layers 1..3 projection with inline BN+leakyReLU -----------------------
// x_raw = xpre[l-1]; y = lrelu(x*Ac+Bc); C = y @ W + bias   (Ac/Bc from BN sums)
__launch_bounds__(256)
__global__ void proj_small_kernel(const float* __restrict__ xp, const float* __restrict__ bnl,
                                  const float* __restrict__ gam, const float* __restrict__ bet,
                                  const float* __restrict__ W, const float* __restrict__ bias,
                                  __bf16* __restrict__ C)
{
  __shared__ float ws[20*160];
  __shared__ float xs[16*20];
  __shared__ float Ac[20], Bc[20];
  const int t = threadIdx.x;
  const int n0 = blockIdx.x * 16;
#pragma unroll
  for (int i = 0; i < 13; i++) {
    int idx = t + i*256;
    if (idx < 3200) ws[idx] = W[idx];
  }
  if (t < 20) {
    float mu  = bnl[t] * (1.f/N_NODES);
    float var = bnl[20+t] * (1.f/N_NODES) - mu*mu;
    float a = rsqrtf(var + 1e-5f) * gam[t];
    Ac[t] = a; Bc[t] = bet[t] - mu*a;
  }
  __syncthreads();
#pragma unroll
  for (int i = 0; i < 2; i++) {
    int idx = t + i*256;
    if (idx < 320) {
      int nl = idx / 20, k = idx % 20;
      int n = n0 + nl;
      float x = (n < N_NODES) ? xp[(size_t)n*D + k] : 0.f;
      float y = x*Ac[k] + Bc[k];
      xs[idx] = (y > 0.f) ? y : 0.01f*y;
    }
  }
  __syncthreads();
#pragma unroll
  for (int i = 0; i < 10; i++) {
    int idx = t + i*256;
    int nl = idx / NCOL, col = idx % NCOL;
    int n = n0 + nl;
    if (n < N_NODES) {
      float acc = bias[col];
#pragma unroll
      for (int k = 0; k < 20; k++) acc += xs[nl*20 + k] * ws[k*NCOL + col];
      C[(size_t)n*NCOL + col] = (__bf16)acc;
    }
  }
}

// ---------------- fused attention + combine + BN partial sums ---------------------------
// One 16-lane group per (node, edge-type): 16 groups/block -> 8 nodes/block.
// No-max softmax (shift-invariant; logits |.|<~25, clamp 80 guards overflow).
__launch_bounds__(256)
__global__ void attn_fused(const int* __restrict__ rp0, const int* __restrict__ adj0,
                           const int* __restrict__ rp1, const int* __restrict__ adj1,
                           const __bf16* __restrict__ proj,
                           const float* __restrict__ w1, const float* __restrict__ w2, int l,
                           float* __restrict__ xpre, float* __restrict__ bn)
{
  __shared__ float outs[16][20];
  __shared__ float ls[40];
  const int t  = threadIdx.x;
  const int g  = t >> 4;              // group 0..15
  const int sl = t & 15;
  const int node = blockIdx.x*8 + (g >> 1);
  const int et   = g & 1;
  const bool valid = node < N_NODES;
  if (t < 40) ls[t] = 0.f;

  float z = 0.f;
  float S[20];
#pragma unroll
  for (int d = 0; d < 20; d++) S[d] = 0.f;

  const __bf16* rq = proj + (size_t)(valid ? node : 0)*NCOL + et*80;

  if (valid) {
    float qf[20];
    {
      bf16x8 q0 = *(const bf16x8*)(rq);
      bf16x8 q1 = *(const bf16x8*)(rq + 8);
      bf16x4 q2 = *(const bf16x4*)(rq + 16);
#pragma unroll
      for (int i = 0; i < 8; i++) { qf[i] = (float)q0[i]; qf[8+i] = (float)q1[i]; }
#pragma unroll
      for (int i = 0; i < 4; i++) qf[16+i] = (float)q2[i];
    }
    const int* rowptr = et ? rp1 : rp0;
    const int* adj    = et ? adj1 : adj0;
    const int beg = rowptr[node], end = rowptr[node+1];

    int i = beg + sl;
    // paired loop: 2 edges per iteration (10 loads in flight)
    for (; i + 16 < end; i += 32) {
      const int s0 = adj[i], s1 = adj[i+16];
      const __bf16* kva = proj + (size_t)s0*NCOL + et*80 + 40;
      const __bf16* kvb = proj + (size_t)s1*NCOL + et*80 + 40;
      bf16x8 a0 = *(const bf16x8*)(kva);
      bf16x8 a1 = *(const bf16x8*)(kva + 8);
      bf16x8 a2 = *(const bf16x8*)(kva + 16);
      bf16x8 a3 = *(const bf16x8*)(kva + 24);
      bf16x8 a4 = *(const bf16x8*)(kva + 32);
      bf16x8 b0 = *(const bf16x8*)(kvb);
      bf16x8 b1 = *(const bf16x8*)(kvb + 8);
      bf16x8 b2 = *(const bf16x8*)(kvb + 16);
      bf16x8 b3 = *(const bf16x8*)(kvb + 24);
      bf16x8 b4 = *(const bf16x8*)(kvb + 32);

      float d0 = 0.f, d1 = 0.f;
#pragma unroll
      for (int j = 0; j < 8; j++) { d0 += qf[j]*(float)a0[j];     d1 += qf[j]*(float)b0[j]; }
#pragma unroll
      for (int j = 0; j < 8; j++) { d0 += qf[8+j]*(float)a1[j];   d1 += qf[8+j]*(float)b1[j]; }
#pragma unroll
      for (int j = 0; j < 4; j++) { d0 += qf[16+j]*(float)a2[j];  d1 += qf[16+j]*(float)b2[j]; }
      const float w0 = __expf(fminf(d0*INV_SQRT_D, 80.f));
      const float w1v= __expf(fminf(d1*INV_SQRT_D, 80.f));
      z += w0 + w1v;
#pragma unroll
      for (int d = 0; d < 4; d++) S[d]    += w0*(float)a2[4+d] + w1v*(float)b2[4+d];
#pragma unroll
      for (int d = 0; d < 8; d++) S[4+d]  += w0*(float)a3[d]   + w1v*(float)b3[d];
#pragma unroll
      for (int d = 0; d < 8; d++) S[12+d] += w0*(float)a4[d]   + w1v*(float)b4[d];
    }
    // tail (at most one edge per lane)
    if (i < end) {
      const int s0 = adj[i];
      const __bf16* kva = proj + (size_t)s0*NCOL + et*80 + 40;
      bf16x8 a0 = *(const bf16x8*)(kva);
      bf16x8 a1 = *(const bf16x8*)(kva + 8);
      bf16x8 a2 = *(const bf16x8*)(kva + 16);
      bf16x8 a3 = *(const bf16x8*)(kva + 24);
      bf16x8 a4 = *(const bf16x8*)(kva + 32);
      float d0 = 0.f;
#pragma unroll
      for (int j = 0; j < 8; j++) d0 += qf[j]*(float)a0[j];
#pragma unroll
      for (int j = 0; j < 8; j++) d0 += qf[8+j]*(float)a1[j];
#pragma unroll
      for (int j = 0; j < 4; j++) d0 += qf[16+j]*(float)a2[j];
      const float w0 = __expf(fminf(d0*INV_SQRT_D, 80.f));
      z += w0;
#pragma unroll
      for (int d = 0; d < 4; d++) S[d]    += w0*(float)a2[4+d];
#pragma unroll
      for (int d = 0; d < 8; d++) S[4+d]  += w0*(float)a3[d];
#pragma unroll
      for (int d = 0; d < 8; d++) S[12+d] += w0*(float)a4[d];
    }
  }

  // plain sum reduce across the 16-lane group
#pragma unroll
  for (int o = 8; o >= 1; o >>= 1) {
    z += __shfl_xor(z, o, 64);
#pragma unroll
    for (int d = 0; d < 20; d++) S[d] += __shfl_xor(S[d], o, 64);
  }

  const float inv = (z > 0.f) ? 1.f/z : 0.f;
  if (valid) {
#pragma unroll
    for (int d = sl; d < 20; d += 16)
      outs[g][d] = S[d]*inv + (float)rq[20 + d];   // + skip term x@Ws+bs
  }
  __syncthreads();

  if (valid && et == 0) {
    const float wa = w1[l], wb = w2[l];
    const float cw0 = wa/(wa+wb), cw1 = wb/(wa+wb);
#pragma unroll
    for (int d = sl; d < 20; d += 16) {
      float x = cw0*outs[g][d] + cw1*outs[g|1][d];
      xpre[(size_t)node*D + d] = x;
      atomicAdd(&ls[d], x);
      atomicAdd(&ls[20+d], x*x);
    }
  }
  __syncthreads();
  if (t < 40) atomicAdd(&bn[t], ls[t]);
}

// ---------------- final: BN+lrelu (inline) on 4 layers, concat @ Wout + bout ------------
__launch_bounds__(256)
__global__ void final_kernel(const float* __restrict__ xpre4, const float* __restrict__ bn,
                             const float* __restrict__ gam, const float* __restrict__ bet,
                             const float* __restrict__ Wout, const float* __restrict__ bout,
                             float* __restrict__ out)
{
  __shared__ float Ac[80], Bc[80], wlds[160];
  const int t = threadIdx.x;
  if (t < 80) {
    int l = t / 20, d = t % 20;
    const float* b = bn + l*80;
    float mu  = b[d] * (1.f/N_NODES);
    float var = b[20+d] * (1.f/N_NODES) - mu*mu;
    float a = rsqrtf(var + 1e-5f) * gam[t];
    Ac[t] = a; Bc[t] = bet[t] - mu*a;
  }
  if (t < 160) wlds[t] = Wout[t];
  __syncthreads();

  const int n = blockIdx.x*256 + t;
  if (n >= N_NODES) return;
  float a0 = bout[0], a1 = bout[1];
#pragma unroll
  for (int l = 0; l < 4; l++) {
    const float* base = xpre4 + (size_t)l*N_NODES*D + (size_t)n*D;
#pragma unroll
    for (int d = 0; d < D; d++) {
      int idx = l*20 + d;
      float y = base[d]*Ac[idx] + Bc[idx];
      y = (y > 0.f) ? y : 0.01f*y;
      a0 += y * wlds[idx*2 + 0];
      a1 += y * wlds[idx*2 + 1];
    }
  }
  out[n*2+0] = a0;
  out[n*2+1] = a1;
}

// ----------------------------------------------------------------------------------------
extern "C" void kernel_launch(void* const* d_in, const int* in_sizes, int n_in,
                              void* d_out, int out_size, void* d_ws, size_t ws_size,
                              hipStream_t stream)
{
  const float* feat = (const float*)d_in[0];
  const int*   same = (const int*)d_in[1];
  const int*   diff = (const int*)d_in[2];
  const float* W0q = (const float*)d_in[3];
  const float* b0q = (const float*)d_in[4];
  const float* W0k = (const float*)d_in[5];
  const float* b0k = (const float*)d_in[6];
  const float* W0v = (const float*)d_in[7];
  const float* b0v = (const float*)d_in[8];
  const float* W0s = (const float*)d_in[9];
  const float* b0s = (const float*)d_in[10];
  const float* Wq  = (const float*)d_in[11];
  const float* bq  = (const float*)d_in[12];
  const float* Wk  = (const float*)d_in[13];
  const float* bk  = (const float*)d_in[14];
  const float* Wv  = (const float*)d_in[15];
  const float* bv  = (const float*)d_in[16];
  const float* Ws_ = (const float*)d_in[17];
  const float* bs_ = (const float*)d_in[18];
  const float* w1  = (const float*)d_in[19];
  const float* w2  = (const float*)d_in[20];
  const float* gamma = (const float*)d_in[21];
  const float* beta  = (const float*)d_in[22];
  const float* Wout  = (const float*)d_in[23];
  const float* bout  = (const float*)d_in[24];

  float* wsf  = (float*)d_ws;
  __bf16*  PROJ  = (__bf16*)wsf;             // 8,000,000 bf16 = 4,000,000 f  [N][160]
  float*   XPRE4 = wsf + 4000000;            // 4,000,000  [4][N][20] pre-BN
  __bf16*  B0bf  = (__bf16*)(wsf + 8000000); //   322,560 bf16 = 161,280 f
  float*   BIAS0 = wsf + 8161280;            //       160
  float*   WL    = wsf + 8161440;            //     9,600  3x[20][160]
  float*   BIASL = wsf + 8171040;            //       480
  float*   BN    = wsf + 8171520;            //       320  4x{sum20,sq20,pad40}
  int*     ib    = (int*)(wsf + 8171840);
  int* DEG  = ib;                            // 100,000  [2][N]
  int* RP0  = ib + 100000;                   //  50,004
  int* RP1  = ib + 150004;                   //  50,004
  int* NX0  = ib + 200008;                   //  50,000
  int* NX1  = ib + 250008;                   //  50,000
  int* ADJ0 = ib + 300008;                   // 1,600,000
  int* ADJ1 = ib + 1900008;                  // 1,600,000

  // pack weights + zero accumulators/degrees
  const int packN = NCOL*KPAD + 160 + 9600 + 480 + 320 + 2*N_NODES;  // 433,120
  pack_kernel<<<(packN + 255)/256, 256, 0, stream>>>(
      W0q, W0k, W0v, W0s, b0q, b0k, b0v, b0s,
      Wq, Wk, Wv, Ws_, bq, bk, bv, bs_,
      B0bf, BIAS0, WL, BIASL, BN, DEG);

  // CSR by dst, per edge type (indices identical across layers)
  hist_kernel<<<(2*E_EDGES + 255)/256, 256, 0, stream>>>(same, diff, DEG);
  scan_kernel<<<2, 1024, 0, stream>>>(DEG, RP0, RP1, NX0, NX1);
  {
    const long nchunk = (2L*E_EDGES + SC_CHUNK - 1) / SC_CHUNK;
    scatter_kernel<<<(int)(nchunk*8), 256, 0, stream>>>(same, diff, NX0, NX1, ADJ0, ADJ1);
  }

  for (int l = 0; l < 4; l++) {
    if (l == 0)
      gemm0_mfma<<<(N_NODES + 127)/128, 512, 0, stream>>>(feat, B0bf, BIAS0, PROJ);
    else
      proj_small_kernel<<<(N_NODES + 15)/16, 256, 0, stream>>>(
          XPRE4 + (size_t)(l-1)*N_NODES*D, BN + (l-1)*80,
          gamma + (l-1)*D, beta + (l-1)*D,
          WL + (size_t)(l-1)*3200, BIASL + (size_t)(l-1)*160, PROJ);

    attn_fused<<<(N_NODES + 7)/8, 256, 0, stream>>>(
        RP0, ADJ0, RP1, ADJ1, PROJ, w1, w2, l, XPRE4 + (size_t)l*N_NODES*D, BN + l*80);
  }

  final_kernel<<<(N_NODES + 255)/256, 256, 0, stream>>>(
      XPRE4, BN, gamma, beta, Wout, bout, (float*)d_out);
}

// Round 6
// 988.929 us; speedup vs baseline: 1.1533x; 1.1533x over previous
//
#include <hip/hip_runtime.h>
#include <math.h>

#define N_NODES 50000
#define E_EDGES 1600000
#define F_IN    2000
#define D       20
#define NCOL    160   // 2 edge types * [q s k v] * 20  (col order: q,s,k,v per edge type)
#define KPAD    2016  // 63 * 32
#define NBNP    64    // BN partial slots

#define INV_SQRT_D 0.22360679774997896f

typedef __bf16 bf16x8 __attribute__((ext_vector_type(8)));
typedef __bf16 bf16x4 __attribute__((ext_vector_type(4)));
typedef float  f32x4  __attribute__((ext_vector_type(4)));

// ---------------- pack weights + zero accumulators --------------------------------------
__global__ void pack_kernel(
    const float* __restrict__ W0q, const float* __restrict__ W0k,
    const float* __restrict__ W0v, const float* __restrict__ W0s,
    const float* __restrict__ b0q, const float* __restrict__ b0k,
    const float* __restrict__ b0v, const float* __restrict__ b0s,
    const float* __restrict__ Wq,  const float* __restrict__ Wk,
    const float* __restrict__ Wv,  const float* __restrict__ Ws_,
    const float* __restrict__ bq,  const float* __restrict__ bk,
    const float* __restrict__ bv,  const float* __restrict__ bs_,
    __bf16* __restrict__ B0, float* __restrict__ bias0,
    float* __restrict__ WL, float* __restrict__ biasL,
    float* __restrict__ bnp, int* __restrict__ deg)
{
  long idx = (long)blockIdx.x * blockDim.x + threadIdx.x;
  if (idx < (long)NCOL*KPAD) {              // B0T: [160][2016] bf16
    int col = (int)(idx / KPAD), k = (int)(idx % KPAD);
    int et = col / 80, r = col % 80, mat = r / 20, d = r % 20;
    const float* w = (mat==0)?W0q:(mat==1)?W0s:(mat==2)?W0k:W0v;
    float v = (k < F_IN) ? w[((size_t)et*F_IN + k)*D + d] : 0.f;
    B0[idx] = (__bf16)v;
    return;
  }
  idx -= (long)NCOL*KPAD;
  if (idx < 160) {                          // bias0
    int col = (int)idx;
    int et = col / 80, r = col % 80, mat = r / 20, d = r % 20;
    const float* b = (mat==0)?b0q:(mat==1)?b0s:(mat==2)?b0k:b0v;
    bias0[col] = b[et*D + d];
    return;
  }
  idx -= 160;
  if (idx < 9600) {                         // WL: 3 x [20][160]
    int l = (int)(idx / 3200), rem = (int)(idx % 3200);
    int k = rem / NCOL, col = rem % NCOL;
    int et = col / 80, r = col % 80, mat = r / 20, d = r % 20;
    const float* w = (mat==0)?Wq:(mat==1)?Ws_:(mat==2)?Wk:Wv;
    WL[idx] = w[(((size_t)l*2 + et)*D + k)*D + d];
    return;
  }
  idx -= 9600;
  if (idx < 480) {                          // biasL: 3 x [160]
    int l = (int)(idx / NCOL), col = (int)(idx % NCOL);
    int et = col / 80, r = col % 80, mat = r / 20, d = r % 20;
    const float* b = (mat==0)?bq:(mat==1)?bs_:(mat==2)?bk:bv;
    biasL[idx] = b[(l*2 + et)*D + d];
    return;
  }
  idx -= 480;
  if (idx < 4*NBNP*40) { bnp[idx] = 0.f; return; } // BN partials: [4][64][40]
  idx -= 4*NBNP*40;
  if (idx < 2*N_NODES) { deg[idx] = 0; return; }
}

// ---------------- CSR build (indices static across layers -> build once per call) -------
__global__ void hist_kernel(const int* __restrict__ same, const int* __restrict__ diff,
                            int* __restrict__ deg)
{
  long i = (long)blockIdx.x * blockDim.x + threadIdx.x;
  if (i >= 2L*E_EDGES) return;
  int et = (i >= E_EDGES) ? 1 : 0;
  long e = i - (long)et*E_EDGES;
  const int* ix = et ? diff : same;
  int dst = ix[E_EDGES + e];
  atomicAdd(&deg[(size_t)et*N_NODES + dst], 1);
}

__global__ void scan_kernel(const int* __restrict__ deg,
                            int* __restrict__ rowptr0, int* __restrict__ rowptr1,
                            int* __restrict__ next0, int* __restrict__ next1)
{
  const int et = blockIdx.x;
  const int* dg = deg + (size_t)et*N_NODES;
  int* rp = et ? rowptr1 : rowptr0;
  int* np = et ? next1 : next0;
  __shared__ int part[1024];
  const int t = threadIdx.x;
  const int per = (N_NODES + 1023) / 1024;  // 49
  const int b = t * per;
  const int e = (b + per < N_NODES) ? (b + per) : N_NODES;
  int s = 0;
  for (int i = b; i < e; i++) s += dg[i];
  part[t] = s;
  __syncthreads();
  for (int o = 1; o < 1024; o <<= 1) {
    int v = (t >= o) ? part[t-o] : 0;
    __syncthreads();
    part[t] += v;
    __syncthreads();
  }
  int run = (t == 0) ? 0 : part[t-1];
  for (int i = b; i < e; i++) {
    rp[i] = run; np[i] = run;
    run += dg[i];
  }
  if (t == 0) rp[N_NODES] = part[1023];
}

// XCD-partitioned scatter: partition p (= blockIdx&7) owns a contiguous dst range so each
// adj cache line is dirtied from (mostly) one XCD.
#define SC_EPT 16
#define SC_CHUNK (256*SC_EPT)
__global__ void scatter_kernel(const int* __restrict__ same, const int* __restrict__ diff,
                               int* __restrict__ next0, int* __restrict__ next1,
                               int* __restrict__ adj0, int* __restrict__ adj1)
{
  const int part  = blockIdx.x & 7;
  const int chunk = blockIdx.x >> 3;
  const int lo = part * (N_NODES/8);
  const int hi = lo + (N_NODES/8);
  const long i0 = (long)chunk * SC_CHUNK + threadIdx.x;
#pragma unroll
  for (int it = 0; it < SC_EPT; ++it) {
    long i = i0 + (long)it*256;
    if (i >= 2L*E_EDGES) break;
    int et = (i >= E_EDGES) ? 1 : 0;
    long e = i - (long)et*E_EDGES;
    const int* ix = et ? diff : same;
    int dst = ix[E_EDGES + e];
    if (dst >= lo && dst < hi) {
      int src = ix[e];
      int* np  = et ? next1 : next0;
      int* adj = et ? adj1  : adj0;
      int pos = atomicAdd(&np[dst], 1);
      adj[pos] = src;
    }
  }
}

// ---------------- layer-0 MFMA GEMM: [50000,2000]fp32 -> bf16 @ [2016,160]bf16 ----------
__launch_bounds__(512)
__global__ void gemm0_mfma(const float* __restrict__ A,
                           const __bf16* __restrict__ Bt,
                           const float* __restrict__ bias,
                           __bf16* __restrict__ C)
{
  __shared__ __bf16 as[128*32];
  const int t    = threadIdx.x;
  const int lane = t & 63;
  const int wid  = t >> 6;
  const int wr   = wid >> 1;        // 0..3 -> rows wr*32
  const int wc   = wid & 1;         // 0..1 -> cols wc*80
  const int rb0  = blockIdx.x * 128;

  const int srow = t >> 2;          // staging: row 0..127
  const int skc  = (t & 3) * 8;     // k chunk of 8
  const int arow = rb0 + srow;
  const float* aptr = A + (size_t)arow * F_IN;

  const int lrow = lane & 15;       // frag row/col within 16
  const int lkb  = (lane >> 4) * 8; // k sub-block

  f32x4 acc[2][5];
#pragma unroll
  for (int i = 0; i < 2; i++)
#pragma unroll
    for (int j = 0; j < 5; j++) acc[i][j] = (f32x4){0.f,0.f,0.f,0.f};

  float4 p0, p1;
  auto loadA = [&](int k0) {
    int k = k0 + skc;
    if (arow < N_NODES) {
      if (k + 8 <= F_IN) {
        p0 = *(const float4*)(aptr + k);
        p1 = *(const float4*)(aptr + k + 4);
      } else {
        float tmp[8];
#pragma unroll
        for (int i = 0; i < 8; i++) tmp[i] = (k + i < F_IN) ? aptr[k + i] : 0.f;
        p0 = make_float4(tmp[0],tmp[1],tmp[2],tmp[3]);
        p1 = make_float4(tmp[4],tmp[5],tmp[6],tmp[7]);
      }
    } else {
      p0 = make_float4(0,0,0,0); p1 = p0;
    }
  };

  loadA(0);
  for (int s = 0; s < 63; s++) {
    bf16x8 h;
    h[0]=(__bf16)p0.x; h[1]=(__bf16)p0.y; h[2]=(__bf16)p0.z; h[3]=(__bf16)p0.w;
    h[4]=(__bf16)p1.x; h[5]=(__bf16)p1.y; h[6]=(__bf16)p1.z; h[7]=(__bf16)p1.w;
    *(bf16x8*)&as[srow*32 + skc] = h;
    __syncthreads();
    if (s + 1 < 63) loadA((s + 1) * 32);

    bf16x8 af[2];
#pragma unroll
    for (int rf = 0; rf < 2; rf++)
      af[rf] = *(bf16x8*)&as[(wr*32 + rf*16 + lrow)*32 + lkb];
    bf16x8 bfr[5];
#pragma unroll
    for (int cf = 0; cf < 5; cf++)
      bfr[cf] = *(const bf16x8*)(Bt + (size_t)(wc*80 + cf*16 + lrow)*KPAD + s*32 + lkb);
#pragma unroll
    for (int rf = 0; rf < 2; rf++)
#pragma unroll
      for (int cf = 0; cf < 5; cf++)
        acc[rf][cf] = __builtin_amdgcn_mfma_f32_16x16x32_bf16(af[rf], bfr[cf], acc[rf][cf], 0, 0, 0);
    __syncthreads();
  }

  // epilogue: C/D layout col=lane&15, row=(lane>>4)*4 + j ; C is bf16 [N][160]
#pragma unroll
  for (int rf = 0; rf < 2; rf++) {
#pragma unroll
    for (int cf = 0; cf < 5; cf++) {
      int col = wc*80 + cf*16 + lrow;
      float bv = bias[col];
#pragma unroll
      for (int j = 0; j < 4; j++) {
        int r = rb0 + wr*32 + rf*16 + (lane >> 4)*4 + j;
        if (r < N_NODES) C[(size_t)r*NCOL + col] = (__bf16)(acc[rf][cf][j] + bv);
      }
    }
  }
}

// ---------------- layers 1..3 projection with inline BN+leakyReLU -----------------------
// x_raw = xpre[l-1]; y = lrelu(x*Ac+Bc); C = y @ W + bias   (Ac/Bc from BN partial slots)
__launch_bounds__(256)
__global__ void proj_small_kernel(const float* __restrict__ xp, const float* __restrict__ bnl,
                                  const float* __restrict__ gam, const float* __restrict__ bet,
                                  const float* __restrict__ W, const float* __restrict__ bias,
                                  __bf16* __restrict__ C)
{
  __shared__ float ws[20*160];
  __shared__ float xs[16*20];
  __shared__ float Ac[20], Bc[20];
  const int t = threadIdx.x;
  const int n0 = blockIdx.x * 16;
#pragma unroll
  for (int i = 0; i < 13; i++) {
    int idx = t + i*256;
    if (idx < 3200) ws[idx] = W[idx];
  }
  if (t < 20) {
    float s1 = 0.f, s2 = 0.f;
    for (int s = 0; s < NBNP; s++) { s1 += bnl[s*40 + t]; s2 += bnl[s*40 + 20 + t]; }
    float mu  = s1 * (1.f/N_NODES);
    float var = s2 * (1.f/N_NODES) - mu*mu;
    float a = rsqrtf(var + 1e-5f) * gam[t];
    Ac[t] = a; Bc[t] = bet[t] - mu*a;
  }
  __syncthreads();
#pragma unroll
  for (int i = 0; i < 2; i++) {
    int idx = t + i*256;
    if (idx < 320) {
      int nl = idx / 20, k = idx % 20;
      int n = n0 + nl;
      float x = (n < N_NODES) ? xp[(size_t)n*D + k] : 0.f;
      float y = x*Ac[k] + Bc[k];
      xs[idx] = (y > 0.f) ? y : 0.01f*y;
    }
  }
  __syncthreads();
#pragma unroll
  for (int i = 0; i < 10; i++) {
    int idx = t + i*256;
    int nl = idx / NCOL, col = idx % NCOL;
    int n = n0 + nl;
    if (n < N_NODES) {
      float acc = bias[col];
#pragma unroll
      for (int k = 0; k < 20; k++) acc += xs[nl*20 + k] * ws[k*NCOL + col];
      C[(size_t)n*NCOL + col] = (__bf16)acc;
    }
  }
}

// ---------------- fused attention + combine + BN partial sums ---------------------------
// ONE WAVE PER NODE: lanes 0-31 do edge-type 0, lanes 32-63 edge-type 1.
// Mean degree 32 -> one edge per lane, single gather round.  No-max softmax
// (shift-invariant; |logit| < ~25, clamp 80 guards overflow).
__launch_bounds__(256)
__global__ void attn_fused(const int* __restrict__ rp0, const int* __restrict__ adj0,
                           const int* __restrict__ rp1, const int* __restrict__ adj1,
                           const __bf16* __restrict__ proj,
                           const float* __restrict__ w1, const float* __restrict__ w2, int l,
                           float* __restrict__ xpre, float* __restrict__ bnp)
{
  __shared__ float xnode[4][20];
  const int t    = threadIdx.x;
  const int wv   = t >> 6;
  const int lane = t & 63;
  const int half = lane >> 5;         // edge type
  const int sl   = lane & 31;
  const int node = blockIdx.x*4 + wv; // grid = 12500 exactly, N = 50000

  const int* rowptr = half ? rp1 : rp0;
  const int* adj    = half ? adj1 : adj0;
  const __bf16* rq  = proj + (size_t)node*NCOL + half*80;

  float qf[20];
  {
    bf16x8 q0 = *(const bf16x8*)(rq);
    bf16x8 q1 = *(const bf16x8*)(rq + 8);
    bf16x4 q2 = *(const bf16x4*)(rq + 16);
#pragma unroll
    for (int i = 0; i < 8; i++) { qf[i] = (float)q0[i]; qf[8+i] = (float)q1[i]; }
#pragma unroll
    for (int i = 0; i < 4; i++) qf[16+i] = (float)q2[i];
  }

  const int beg = rowptr[node], end = rowptr[node+1];
  float z = 0.f;
  float S[20];
#pragma unroll
  for (int d = 0; d < 20; d++) S[d] = 0.f;

  for (int i = beg + sl; i < end; i += 32) {
    const int src = adj[i];
    const __bf16* kv = proj + (size_t)src*NCOL + half*80 + 40;  // k(20) v(20), 16B aligned
    bf16x8 a0 = *(const bf16x8*)(kv);
    bf16x8 a1 = *(const bf16x8*)(kv + 8);
    bf16x8 a2 = *(const bf16x8*)(kv + 16);
    bf16x8 a3 = *(const bf16x8*)(kv + 24);
    bf16x8 a4 = *(const bf16x8*)(kv + 32);
    float d0 = 0.f;
#pragma unroll
    for (int j = 0; j < 8; j++) d0 += qf[j]     * (float)a0[j];
#pragma unroll
    for (int j = 0; j < 8; j++) d0 += qf[8 + j] * (float)a1[j];
#pragma unroll
    for (int j = 0; j < 4; j++) d0 += qf[16 + j]* (float)a2[j];
    const float w0 = __expf(fminf(d0*INV_SQRT_D, 80.f));
    z += w0;
#pragma unroll
    for (int d = 0; d < 4; d++) S[d]     += w0*(float)a2[4+d];
#pragma unroll
    for (int d = 0; d < 8; d++) S[4+d]   += w0*(float)a3[d];
#pragma unroll
    for (int d = 0; d < 8; d++) S[12+d]  += w0*(float)a4[d];
  }

  // butterfly sum within each 32-lane half (all lanes end with the result)
#pragma unroll
  for (int o = 16; o >= 1; o >>= 1) {
    z += __shfl_xor(z, o, 64);
#pragma unroll
    for (int d = 0; d < 20; d++) S[d] += __shfl_xor(S[d], o, 64);
  }

  // per-et output: S/z + skip (x@Ws+bs at cols 20-39)
  const float inv = (z > 0.f) ? 1.f/z : 0.f;
  float outv[20];
  {
    bf16x4 s0 = *(const bf16x4*)(rq + 20);
    bf16x8 s1 = *(const bf16x8*)(rq + 24);
    bf16x8 s2 = *(const bf16x8*)(rq + 32);
#pragma unroll
    for (int i = 0; i < 4; i++) outv[i] = S[i]*inv + (float)s0[i];
#pragma unroll
    for (int i = 0; i < 8; i++) { outv[4+i]  = S[4+i]*inv  + (float)s1[i];
                                  outv[12+i] = S[12+i]*inv + (float)s2[i]; }
  }

  // cross-half combine (lane<32 pairs with lane+32)
  const float wa = w1[l], wb = w2[l];
  const float c0 = wa/(wa+wb), c1 = wb/(wa+wb);
  const float cme = half ? c1 : c0;
  const float cot = half ? c0 : c1;
  float x[20];
#pragma unroll
  for (int d = 0; d < 20; d++) {
    float o2 = __shfl_xor(outv[d], 32, 64);
    x[d] = cme*outv[d] + cot*o2;
  }

  if (lane == 0) {
    float* xo = xpre + (size_t)node*D;
#pragma unroll
    for (int j = 0; j < 5; j++) {
      float4 o4 = make_float4(x[4*j], x[4*j+1], x[4*j+2], x[4*j+3]);
      *(float4*)(xo + 4*j) = o4;
    }
#pragma unroll
    for (int d = 0; d < 20; d++) xnode[wv][d] = x[d];
  }
  __syncthreads();

  if (t < 20) {
    float s1 = xnode[0][t] + xnode[1][t] + xnode[2][t] + xnode[3][t];
    float s2 = xnode[0][t]*xnode[0][t] + xnode[1][t]*xnode[1][t]
             + xnode[2][t]*xnode[2][t] + xnode[3][t]*xnode[3][t];
    float* slot = bnp + (blockIdx.x & (NBNP-1))*40;
    atomicAdd(&slot[t], s1);
    atomicAdd(&slot[20 + t], s2);
  }
}

// ---------------- final: BN+lrelu (inline) on 4 layers, concat @ Wout + bout ------------
__launch_bounds__(256)
__global__ void final_kernel(const float* __restrict__ xpre4, const float* __restrict__ bnp,
                             const float* __restrict__ gam, const float* __restrict__ bet,
                             const float* __restrict__ Wout, const float* __restrict__ bout,
                             float* __restrict__ out)
{
  __shared__ float Ac[80], Bc[80], wlds[160];
  const int t = threadIdx.x;
  if (t < 80) {
    int l = t / 20, d = t % 20;
    const float* b = bnp + l*(NBNP*40);
    float s1 = 0.f, s2 = 0.f;
    for (int s = 0; s < NBNP; s++) { s1 += b[s*40 + d]; s2 += b[s*40 + 20 + d]; }
    float mu  = s1 * (1.f/N_NODES);
    float var = s2 * (1.f/N_NODES) - mu*mu;
    float a = rsqrtf(var + 1e-5f) * gam[t];
    Ac[t] = a; Bc[t] = bet[t] - mu*a;
  }
  if (t < 160) wlds[t] = Wout[t];
  __syncthreads();

  const int n = blockIdx.x*256 + t;
  if (n >= N_NODES) return;
  float a0 = bout[0], a1 = bout[1];
#pragma unroll
  for (int l = 0; l < 4; l++) {
    const float* base = xpre4 + (size_t)l*N_NODES*D + (size_t)n*D;
#pragma unroll
    for (int d = 0; d < D; d++) {
      int idx = l*20 + d;
      float y = base[d]*Ac[idx] + Bc[idx];
      y = (y > 0.f) ? y : 0.01f*y;
      a0 += y * wlds[idx*2 + 0];
      a1 += y * wlds[idx*2 + 1];
    }
  }
  out[n*2+0] = a0;
  out[n*2+1] = a1;
}

// ----------------------------------------------------------------------------------------
extern "C" void kernel_launch(void* const* d_in, const int* in_sizes, int n_in,
                              void* d_out, int out_size, void* d_ws, size_t ws_size,
                              hipStream_t stream)
{
  const float* feat = (const float*)d_in[0];
  const int*   same = (const int*)d_in[1];
  const int*   diff = (const int*)d_in[2];
  const float* W0q = (const float*)d_in[3];
  const float* b0q = (const float*)d_in[4];
  const float* W0k = (const float*)d_in[5];
  const float* b0k = (const float*)d_in[6];
  const float* W0v = (const float*)d_in[7];
  const float* b0v = (const float*)d_in[8];
  const float* W0s = (const float*)d_in[9];
  const float* b0s = (const float*)d_in[10];
  const float* Wq  = (const float*)d_in[11];
  const float* bq  = (const float*)d_in[12];
  const float* Wk  = (const float*)d_in[13];
  const float* bk  = (const float*)d_in[14];
  const float* Wv  = (const float*)d_in[15];
  const float* bv  = (const float*)d_in[16];
  const float* Ws_ = (const float*)d_in[17];
  const float* bs_ = (const float*)d_in[18];
  const float* w1  = (const float*)d_in[19];
  const float* w2  = (const float*)d_in[20];
  const float* gamma = (const float*)d_in[21];
  const float* beta  = (const float*)d_in[22];
  const float* Wout  = (const float*)d_in[23];
  const float* bout  = (const float*)d_in[24];

  float* wsf  = (float*)d_ws;
  __bf16*  PROJ  = (__bf16*)wsf;             // 8,000,000 bf16 = 4,000,000 f  [N][160]
  float*   XPRE4 = wsf + 4000000;            // 4,000,000  [4][N][20] pre-BN
  __bf16*  B0bf  = (__bf16*)(wsf + 8000000); //   322,560 bf16 = 161,280 f
  float*   BIAS0 = wsf + 8161280;            //       160
  float*   WL    = wsf + 8161440;            //     9,600  3x[20][160]
  float*   BIASL = wsf + 8171040;            //       480
  float*   BNP   = wsf + 8171520;            //    10,240  [4][64][40] BN partials
  int*     ib    = (int*)(wsf + 8181760);
  int* DEG  = ib;                            // 100,000  [2][N]
  int* RP0  = ib + 100000;                   //  50,004
  int* RP1  = ib + 150004;                   //  50,004
  int* NX0  = ib + 200008;                   //  50,000
  int* NX1  = ib + 250008;                   //  50,000
  int* ADJ0 = ib + 300008;                   // 1,600,000
  int* ADJ1 = ib + 1900008;                  // 1,600,000

  // pack weights + zero BN partials/degrees
  const int packN = NCOL*KPAD + 160 + 9600 + 480 + 4*NBNP*40 + 2*N_NODES;  // 443,040
  pack_kernel<<<(packN + 255)/256, 256, 0, stream>>>(
      W0q, W0k, W0v, W0s, b0q, b0k, b0v, b0s,
      Wq, Wk, Wv, Ws_, bq, bk, bv, bs_,
      B0bf, BIAS0, WL, BIASL, BNP, DEG);

  // CSR by dst, per edge type (indices identical across layers)
  hist_kernel<<<(2*E_EDGES + 255)/256, 256, 0, stream>>>(same, diff, DEG);
  scan_kernel<<<2, 1024, 0, stream>>>(DEG, RP0, RP1, NX0, NX1);
  {
    const long nchunk = (2L*E_EDGES + SC_CHUNK - 1) / SC_CHUNK;
    scatter_kernel<<<(int)(nchunk*8), 256, 0, stream>>>(same, diff, NX0, NX1, ADJ0, ADJ1);
  }

  for (int l = 0; l < 4; l++) {
    if (l == 0)
      gemm0_mfma<<<(N_NODES + 127)/128, 512, 0, stream>>>(feat, B0bf, BIAS0, PROJ);
    else
      proj_small_kernel<<<(N_NODES + 15)/16, 256, 0, stream>>>(
          XPRE4 + (size_t)(l-1)*N_NODES*D, BNP + (l-1)*(NBNP*40),
          gamma + (l-1)*D, beta + (l-1)*D,
          WL + (size_t)(l-1)*3200, BIASL + (size_t)(l-1)*160, PROJ);

    attn_fused<<<N_NODES/4, 256, 0, stream>>>(
        RP0, ADJ0, RP1, ADJ1, PROJ, w1, w2, l,
        XPRE4 + (size_t)l*N_NODES*D, BNP + l*(NBNP*40));
  }

  final_kernel<<<(N_NODES + 255)/256, 256, 0, stream>>>(
      XPRE4, BNP, gamma, beta, Wout, bout, (float*)d_out);
}

// Round 7
// 986.863 us; speedup vs baseline: 1.1557x; 1.0021x over previous
//
#include <hip/hip_runtime.h>
#include <math.h>

#define N_NODES 50000
#define E_EDGES 1600000
#define F_IN    2000
#define D       20
#define NCOL    160   // 2 edge types * [q s k v] * 20
#define KPAD    2016  // 63 * 32
#define NBNP    64    // BN partial slots

#define INV_SQRT_D 0.22360679774997896f

typedef __bf16 bf16x8 __attribute__((ext_vector_type(8)));
typedef __bf16 bf16x4 __attribute__((ext_vector_type(4)));
typedef float  f32x4  __attribute__((ext_vector_type(4)));

// Output routing: col -> QS[node][et*40 + mat*20 + d] (mat 0=q,1=s)
//                     -> KV[et][node*64 + (mat-2)*20 + d] (mat 2=k,3=v; 128B rows)

// ---------------- pack weights + zero accumulators --------------------------------------
__global__ void pack_kernel(
    const float* __restrict__ W0q, const float* __restrict__ W0k,
    const float* __restrict__ W0v, const float* __restrict__ W0s,
    const float* __restrict__ b0q, const float* __restrict__ b0k,
    const float* __restrict__ b0v, const float* __restrict__ b0s,
    const float* __restrict__ Wq,  const float* __restrict__ Wk,
    const float* __restrict__ Wv,  const float* __restrict__ Ws_,
    const float* __restrict__ bq,  const float* __restrict__ bk,
    const float* __restrict__ bv,  const float* __restrict__ bs_,
    __bf16* __restrict__ B0, float* __restrict__ bias0,
    float* __restrict__ WL, float* __restrict__ biasL,
    float* __restrict__ bnp, int* __restrict__ deg)
{
  long idx = (long)blockIdx.x * blockDim.x + threadIdx.x;
  if (idx < (long)NCOL*KPAD) {              // B0T: [160][2016] bf16
    int col = (int)(idx / KPAD), k = (int)(idx % KPAD);
    int et = col / 80, r = col % 80, mat = r / 20, d = r % 20;
    const float* w = (mat==0)?W0q:(mat==1)?W0s:(mat==2)?W0k:W0v;
    float v = (k < F_IN) ? w[((size_t)et*F_IN + k)*D + d] : 0.f;
    B0[idx] = (__bf16)v;
    return;
  }
  idx -= (long)NCOL*KPAD;
  if (idx < 160) {                          // bias0
    int col = (int)idx;
    int et = col / 80, r = col % 80, mat = r / 20, d = r % 20;
    const float* b = (mat==0)?b0q:(mat==1)?b0s:(mat==2)?b0k:b0v;
    bias0[col] = b[et*D + d];
    return;
  }
  idx -= 160;
  if (idx < 9600) {                         // WL: 3 x [20][160]
    int l = (int)(idx / 3200), rem = (int)(idx % 3200);
    int k = rem / NCOL, col = rem % NCOL;
    int et = col / 80, r = col % 80, mat = r / 20, d = r % 20;
    const float* w = (mat==0)?Wq:(mat==1)?Ws_:(mat==2)?Wk:Wv;
    WL[idx] = w[(((size_t)l*2 + et)*D + k)*D + d];
    return;
  }
  idx -= 9600;
  if (idx < 480) {                          // biasL: 3 x [160]
    int l = (int)(idx / NCOL), col = (int)(idx % NCOL);
    int et = col / 80, r = col % 80, mat = r / 20, d = r % 20;
    const float* b = (mat==0)?bq:(mat==1)?bs_:(mat==2)?bk:bv;
    biasL[idx] = b[(l*2 + et)*D + d];
    return;
  }
  idx -= 480;
  if (idx < 4*NBNP*40) { bnp[idx] = 0.f; return; } // BN partials: [4][64][40]
  idx -= 4*NBNP*40;
  if (idx < 2*N_NODES) { deg[idx] = 0; return; }
}

// ---------------- CSR build (indices static across layers -> build once per call) -------
__global__ void hist_kernel(const int* __restrict__ same, const int* __restrict__ diff,
                            int* __restrict__ deg)
{
  long i = (long)blockIdx.x * blockDim.x + threadIdx.x;
  if (i >= 2L*E_EDGES) return;
  int et = (i >= E_EDGES) ? 1 : 0;
  long e = i - (long)et*E_EDGES;
  const int* ix = et ? diff : same;
  int dst = ix[E_EDGES + e];
  atomicAdd(&deg[(size_t)et*N_NODES + dst], 1);
}

__global__ void scan_kernel(const int* __restrict__ deg,
                            int* __restrict__ rowptr0, int* __restrict__ rowptr1,
                            int* __restrict__ next0, int* __restrict__ next1)
{
  const int et = blockIdx.x;
  const int* dg = deg + (size_t)et*N_NODES;
  int* rp = et ? rowptr1 : rowptr0;
  int* np = et ? next1 : next0;
  __shared__ int part[1024];
  const int t = threadIdx.x;
  const int per = (N_NODES + 1023) / 1024;  // 49
  const int b = t * per;
  const int e = (b + per < N_NODES) ? (b + per) : N_NODES;
  int s = 0;
  for (int i = b; i < e; i++) s += dg[i];
  part[t] = s;
  __syncthreads();
  for (int o = 1; o < 1024; o <<= 1) {
    int v = (t >= o) ? part[t-o] : 0;
    __syncthreads();
    part[t] += v;
    __syncthreads();
  }
  int run = (t == 0) ? 0 : part[t-1];
  for (int i = b; i < e; i++) {
    rp[i] = run; np[i] = run;
    run += dg[i];
  }
  if (t == 0) rp[N_NODES] = part[1023];
}

// XCD-partitioned scatter
#define SC_EPT 16
#define SC_CHUNK (256*SC_EPT)
__global__ void scatter_kernel(const int* __restrict__ same, const int* __restrict__ diff,
                               int* __restrict__ next0, int* __restrict__ next1,
                               int* __restrict__ adj0, int* __restrict__ adj1)
{
  const int part  = blockIdx.x & 7;
  const int chunk = blockIdx.x >> 3;
  const int lo = part * (N_NODES/8);
  const int hi = lo + (N_NODES/8);
  const long i0 = (long)chunk * SC_CHUNK + threadIdx.x;
#pragma unroll
  for (int it = 0; it < SC_EPT; ++it) {
    long i = i0 + (long)it*256;
    if (i >= 2L*E_EDGES) break;
    int et = (i >= E_EDGES) ? 1 : 0;
    long e = i - (long)et*E_EDGES;
    const int* ix = et ? diff : same;
    int dst = ix[E_EDGES + e];
    if (dst >= lo && dst < hi) {
      int src = ix[e];
      int* np  = et ? next1 : next0;
      int* adj = et ? adj1  : adj0;
      int pos = atomicAdd(&np[dst], 1);
      adj[pos] = src;
    }
  }
}

// ---------------- layer-0 MFMA GEMM: [50000,2000]fp32 -> bf16 @ [2016,160]bf16 ----------
__launch_bounds__(512)
__global__ void gemm0_mfma(const float* __restrict__ A,
                           const __bf16* __restrict__ Bt,
                           const float* __restrict__ bias,
                           __bf16* __restrict__ QS,
                           __bf16* __restrict__ KV0, __bf16* __restrict__ KV1)
{
  __shared__ __bf16 as[128*32];
  const int t    = threadIdx.x;
  const int lane = t & 63;
  const int wid  = t >> 6;
  const int wr   = wid >> 1;        // 0..3 -> rows wr*32
  const int wc   = wid & 1;         // 0..1 -> cols wc*80
  const int rb0  = blockIdx.x * 128;

  const int srow = t >> 2;          // staging: row 0..127
  const int skc  = (t & 3) * 8;     // k chunk of 8
  const int arow = rb0 + srow;
  const float* aptr = A + (size_t)arow * F_IN;

  const int lrow = lane & 15;       // frag row/col within 16
  const int lkb  = (lane >> 4) * 8; // k sub-block

  f32x4 acc[2][5];
#pragma unroll
  for (int i = 0; i < 2; i++)
#pragma unroll
    for (int j = 0; j < 5; j++) acc[i][j] = (f32x4){0.f,0.f,0.f,0.f};

  float4 p0, p1;
  auto loadA = [&](int k0) {
    int k = k0 + skc;
    if (arow < N_NODES) {
      if (k + 8 <= F_IN) {
        p0 = *(const float4*)(aptr + k);
        p1 = *(const float4*)(aptr + k + 4);
      } else {
        float tmp[8];
#pragma unroll
        for (int i = 0; i < 8; i++) tmp[i] = (k + i < F_IN) ? aptr[k + i] : 0.f;
        p0 = make_float4(tmp[0],tmp[1],tmp[2],tmp[3]);
        p1 = make_float4(tmp[4],tmp[5],tmp[6],tmp[7]);
      }
    } else {
      p0 = make_float4(0,0,0,0); p1 = p0;
    }
  };

  loadA(0);
  for (int s = 0; s < 63; s++) {
    bf16x8 h;
    h[0]=(__bf16)p0.x; h[1]=(__bf16)p0.y; h[2]=(__bf16)p0.z; h[3]=(__bf16)p0.w;
    h[4]=(__bf16)p1.x; h[5]=(__bf16)p1.y; h[6]=(__bf16)p1.z; h[7]=(__bf16)p1.w;
    *(bf16x8*)&as[srow*32 + skc] = h;
    __syncthreads();
    if (s + 1 < 63) loadA((s + 1) * 32);

    bf16x8 af[2];
#pragma unroll
    for (int rf = 0; rf < 2; rf++)
      af[rf] = *(bf16x8*)&as[(wr*32 + rf*16 + lrow)*32 + lkb];
    bf16x8 bfr[5];
#pragma unroll
    for (int cf = 0; cf < 5; cf++)
      bfr[cf] = *(const bf16x8*)(Bt + (size_t)(wc*80 + cf*16 + lrow)*KPAD + s*32 + lkb);
#pragma unroll
    for (int rf = 0; rf < 2; rf++)
#pragma unroll
      for (int cf = 0; cf < 5; cf++)
        acc[rf][cf] = __builtin_amdgcn_mfma_f32_16x16x32_bf16(af[rf], bfr[cf], acc[rf][cf], 0, 0, 0);
    __syncthreads();
  }

  // epilogue: C/D layout col=lane&15, row=(lane>>4)*4 + j ; route to QS/KV
#pragma unroll
  for (int rf = 0; rf < 2; rf++) {
#pragma unroll
    for (int cf = 0; cf < 5; cf++) {
      int col = wc*80 + cf*16 + lrow;
      int et = col / 80, r = col % 80, mat = r / 20, d = r % 20;
      float bv = bias[col];
      __bf16* kvp = et ? KV1 : KV0;
#pragma unroll
      for (int j = 0; j < 4; j++) {
        int row = rb0 + wr*32 + rf*16 + (lane >> 4)*4 + j;
        if (row < N_NODES) {
          __bf16 val = (__bf16)(acc[rf][cf][j] + bv);
          if (mat < 2) QS[(size_t)row*80 + et*40 + mat*20 + d] = val;
          else         kvp[(size_t)row*64 + (mat-2)*20 + d]   = val;
        }
      }
    }
  }
}

// ---------------- layers 1..3 projection with inline BN+leakyReLU -----------------------
__launch_bounds__(256)
__global__ void proj_small_kernel(const float* __restrict__ xp, const float* __restrict__ bnl,
                                  const float* __restrict__ gam, const float* __restrict__ bet,
                                  const float* __restrict__ W, const float* __restrict__ bias,
                                  __bf16* __restrict__ QS,
                                  __bf16* __restrict__ KV0, __bf16* __restrict__ KV1)
{
  __shared__ float ws[20*160];
  __shared__ float xs[16*20];
  __shared__ float Ac[20], Bc[20];
  const int t = threadIdx.x;
  const int n0 = blockIdx.x * 16;
#pragma unroll
  for (int i = 0; i < 13; i++) {
    int idx = t + i*256;
    if (idx < 3200) ws[idx] = W[idx];
  }
  if (t < 20) {
    float s1 = 0.f, s2 = 0.f;
    for (int s = 0; s < NBNP; s++) { s1 += bnl[s*40 + t]; s2 += bnl[s*40 + 20 + t]; }
    float mu  = s1 * (1.f/N_NODES);
    float var = s2 * (1.f/N_NODES) - mu*mu;
    float a = rsqrtf(var + 1e-5f) * gam[t];
    Ac[t] = a; Bc[t] = bet[t] - mu*a;
  }
  __syncthreads();
#pragma unroll
  for (int i = 0; i < 2; i++) {
    int idx = t + i*256;
    if (idx < 320) {
      int nl = idx / 20, k = idx % 20;
      int n = n0 + nl;
      float x = (n < N_NODES) ? xp[(size_t)n*D + k] : 0.f;
      float y = x*Ac[k] + Bc[k];
      xs[idx] = (y > 0.f) ? y : 0.01f*y;
    }
  }
  __syncthreads();
#pragma unroll
  for (int i = 0; i < 10; i++) {
    int idx = t + i*256;
    int nl = idx / NCOL, col = idx % NCOL;
    int n = n0 + nl;
    if (n < N_NODES) {
      float acc = bias[col];
#pragma unroll
      for (int k = 0; k < 20; k++) acc += xs[nl*20 + k] * ws[k*NCOL + col];
      int et = col / 80, r = col % 80, mat = r / 20, d = r % 20;
      __bf16 val = (__bf16)acc;
      if (mat < 2) QS[(size_t)n*80 + et*40 + mat*20 + d] = val;
      else         (et ? KV1 : KV0)[(size_t)n*64 + (mat-2)*20 + d] = val;
    }
  }
}

// ---------------- fused attention + combine + BN partial sums ---------------------------
// ONE WAVE PER NODE: lanes 0-31 et0, lanes 32-63 et1; one edge per lane (mean deg 32).
// KV rows are 128B-aligned single cache lines. No-max softmax (clamp 80).
__launch_bounds__(256)
__global__ void attn_fused(const int* __restrict__ rp0, const int* __restrict__ adj0,
                           const int* __restrict__ rp1, const int* __restrict__ adj1,
                           const __bf16* __restrict__ QS,
                           const __bf16* __restrict__ KV0, const __bf16* __restrict__ KV1,
                           const float* __restrict__ w1, const float* __restrict__ w2, int l,
                           float* __restrict__ xpre, float* __restrict__ bnp)
{
  __shared__ float xnode[4][20];
  const int t    = threadIdx.x;
  const int wv   = t >> 6;
  const int lane = t & 63;
  const int half = lane >> 5;         // edge type
  const int sl   = lane & 31;
  const int node = blockIdx.x*4 + wv; // grid = 12500 exactly

  const int* rowptr = half ? rp1 : rp0;
  const int* adj    = half ? adj1 : adj0;
  const __bf16* kvb = half ? KV1 : KV0;
  const __bf16* rq  = QS + (size_t)node*80 + half*40;   // q[0..20) s[20..40)

  float qf[20];
  {
    bf16x8 q0 = *(const bf16x8*)(rq);
    bf16x8 q1 = *(const bf16x8*)(rq + 8);
    bf16x4 q2 = *(const bf16x4*)(rq + 16);
#pragma unroll
    for (int i = 0; i < 8; i++) { qf[i] = (float)q0[i]; qf[8+i] = (float)q1[i]; }
#pragma unroll
    for (int i = 0; i < 4; i++) qf[16+i] = (float)q2[i];
  }

  const int beg = rowptr[node], end = rowptr[node+1];
  float z = 0.f;
  float S[20];
#pragma unroll
  for (int d = 0; d < 20; d++) S[d] = 0.f;

  for (int i = beg + sl; i < end; i += 32) {
    const int src = adj[i];
    const __bf16* kv = kvb + (size_t)src*64;   // one 128B line: k(20) v(20) pad
    bf16x8 a0 = *(const bf16x8*)(kv);
    bf16x8 a1 = *(const bf16x8*)(kv + 8);
    bf16x8 a2 = *(const bf16x8*)(kv + 16);
    bf16x8 a3 = *(const bf16x8*)(kv + 24);
    bf16x8 a4 = *(const bf16x8*)(kv + 32);
    float d0 = 0.f;
#pragma unroll
    for (int j = 0; j < 8; j++) d0 += qf[j]     * (float)a0[j];
#pragma unroll
    for (int j = 0; j < 8; j++) d0 += qf[8 + j] * (float)a1[j];
#pragma unroll
    for (int j = 0; j < 4; j++) d0 += qf[16 + j]* (float)a2[j];
    const float w0 = __expf(fminf(d0*INV_SQRT_D, 80.f));
    z += w0;
#pragma unroll
    for (int d = 0; d < 4; d++) S[d]     += w0*(float)a2[4+d];
#pragma unroll
    for (int d = 0; d < 8; d++) S[4+d]   += w0*(float)a3[d];
#pragma unroll
    for (int d = 0; d < 8; d++) S[12+d]  += w0*(float)a4[d];
  }

  // butterfly sum within each 32-lane half
#pragma unroll
  for (int o = 16; o >= 1; o >>= 1) {
    z += __shfl_xor(z, o, 64);
#pragma unroll
    for (int d = 0; d < 20; d++) S[d] += __shfl_xor(S[d], o, 64);
  }

  // per-et output: S/z + skip (s at rq+20)
  const float inv = (z > 0.f) ? 1.f/z : 0.f;
  float outv[20];
  {
    bf16x4 s0 = *(const bf16x4*)(rq + 20);
    bf16x8 s1 = *(const bf16x8*)(rq + 24);
    bf16x8 s2 = *(const bf16x8*)(rq + 32);
#pragma unroll
    for (int i = 0; i < 4; i++) outv[i] = S[i]*inv + (float)s0[i];
#pragma unroll
    for (int i = 0; i < 8; i++) { outv[4+i]  = S[4+i]*inv  + (float)s1[i];
                                  outv[12+i] = S[12+i]*inv + (float)s2[i]; }
  }

  // cross-half combine
  const float wa = w1[l], wb = w2[l];
  const float c0 = wa/(wa+wb), c1 = wb/(wa+wb);
  const float cme = half ? c1 : c0;
  const float cot = half ? c0 : c1;
  float x[20];
#pragma unroll
  for (int d = 0; d < 20; d++) {
    float o2 = __shfl_xor(outv[d], 32, 64);
    x[d] = cme*outv[d] + cot*o2;
  }

  if (lane == 0) {
    float* xo = xpre + (size_t)node*D;
#pragma unroll
    for (int j = 0; j < 5; j++) {
      float4 o4 = make_float4(x[4*j], x[4*j+1], x[4*j+2], x[4*j+3]);
      *(float4*)(xo + 4*j) = o4;
    }
#pragma unroll
    for (int d = 0; d < 20; d++) xnode[wv][d] = x[d];
  }
  __syncthreads();

  if (t < 20) {
    float s1 = xnode[0][t] + xnode[1][t] + xnode[2][t] + xnode[3][t];
    float s2 = xnode[0][t]*xnode[0][t] + xnode[1][t]*xnode[1][t]
             + xnode[2][t]*xnode[2][t] + xnode[3][t]*xnode[3][t];
    float* slot = bnp + (blockIdx.x & (NBNP-1))*40;
    atomicAdd(&slot[t], s1);
    atomicAdd(&slot[20 + t], s2);
  }
}

// ---------------- final: BN+lrelu (inline) on 4 layers, concat @ Wout + bout ------------
__launch_bounds__(256)
__global__ void final_kernel(const float* __restrict__ xpre4, const float* __restrict__ bnp,
                             const float* __restrict__ gam, const float* __restrict__ bet,
                             const float* __restrict__ Wout, const float* __restrict__ bout,
                             float* __restrict__ out)
{
  __shared__ float Ac[80], Bc[80], wlds[160];
  const int t = threadIdx.x;
  if (t < 80) {
    int l = t / 20, d = t % 20;
    const float* b = bnp + l*(NBNP*40);
    float s1 = 0.f, s2 = 0.f;
    for (int s = 0; s < NBNP; s++) { s1 += b[s*40 + d]; s2 += b[s*40 + 20 + d]; }
    float mu  = s1 * (1.f/N_NODES);
    float var = s2 * (1.f/N_NODES) - mu*mu;
    float a = rsqrtf(var + 1e-5f) * gam[t];
    Ac[t] = a; Bc[t] = bet[t] - mu*a;
  }
  if (t < 160) wlds[t] = Wout[t];
  __syncthreads();

  const int n = blockIdx.x*256 + t;
  if (n >= N_NODES) return;
  float a0 = bout[0], a1 = bout[1];
#pragma unroll
  for (int l = 0; l < 4; l++) {
    const float* base = xpre4 + (size_t)l*N_NODES*D + (size_t)n*D;
#pragma unroll
    for (int d = 0; d < D; d++) {
      int idx = l*20 + d;
      float y = base[d]*Ac[idx] + Bc[idx];
      y = (y > 0.f) ? y : 0.01f*y;
      a0 += y * wlds[idx*2 + 0];
      a1 += y * wlds[idx*2 + 1];
    }
  }
  out[n*2+0] = a0;
  out[n*2+1] = a1;
}

// ----------------------------------------------------------------------------------------
extern "C" void kernel_launch(void* const* d_in, const int* in_sizes, int n_in,
                              void* d_out, int out_size, void* d_ws, size_t ws_size,
                              hipStream_t stream)
{
  const float* feat = (const float*)d_in[0];
  const int*   same = (const int*)d_in[1];
  const int*   diff = (const int*)d_in[2];
  const float* W0q = (const float*)d_in[3];
  const float* b0q = (const float*)d_in[4];
  const float* W0k = (const float*)d_in[5];
  const float* b0k = (const float*)d_in[6];
  const float* W0v = (const float*)d_in[7];
  const float* b0v = (const float*)d_in[8];
  const float* W0s = (const float*)d_in[9];
  const float* b0s = (const float*)d_in[10];
  const float* Wq  = (const float*)d_in[11];
  const float* bq  = (const float*)d_in[12];
  const float* Wk  = (const float*)d_in[13];
  const float* bk  = (const float*)d_in[14];
  const float* Wv  = (const float*)d_in[15];
  const float* bv  = (const float*)d_in[16];
  const float* Ws_ = (const float*)d_in[17];
  const float* bs_ = (const float*)d_in[18];
  const float* w1  = (const float*)d_in[19];
  const float* w2  = (const float*)d_in[20];
  const float* gamma = (const float*)d_in[21];
  const float* beta  = (const float*)d_in[22];
  const float* Wout  = (const float*)d_in[23];
  const float* bout  = (const float*)d_in[24];

  float* wsf  = (float*)d_ws;
  __bf16*  QS    = (__bf16*)wsf;                 // 4,000,000 bf16 = 2,000,000 f [N][80]
  __bf16*  KV0   = (__bf16*)(wsf + 2000000);     // 3,200,000 bf16 rows of 64 (128B aligned)
  __bf16*  KV1   = (__bf16*)(wsf + 3600000);
  float*   XPRE4 = wsf + 5200000;                // 4,000,000  [4][N][20] pre-BN
  __bf16*  B0bf  = (__bf16*)(wsf + 9200000);     //   322,560 bf16 = 161,280 f
  float*   BIAS0 = wsf + 9361280;                //       160
  float*   WL    = wsf + 9361440;                //     9,600  3x[20][160]
  float*   BIASL = wsf + 9371040;                //       480
  float*   BNP   = wsf + 9371520;                //    10,240  [4][64][40]
  int*     ib    = (int*)(wsf + 9381760);
  int* DEG  = ib;                                // 100,000  [2][N]
  int* RP0  = ib + 100000;                       //  50,004
  int* RP1  = ib + 150004;                       //  50,004
  int* NX0  = ib + 200008;                       //  50,000
  int* NX1  = ib + 250008;                       //  50,000
  int* ADJ0 = ib + 300008;                       // 1,600,000
  int* ADJ1 = ib + 1900008;                      // 1,600,000

  // pack weights + zero BN partials/degrees
  const int packN = NCOL*KPAD + 160 + 9600 + 480 + 4*NBNP*40 + 2*N_NODES;  // 443,040
  pack_kernel<<<(packN + 255)/256, 256, 0, stream>>>(
      W0q, W0k, W0v, W0s, b0q, b0k, b0v, b0s,
      Wq, Wk, Wv, Ws_, bq, bk, bv, bs_,
      B0bf, BIAS0, WL, BIASL, BNP, DEG);

  // CSR by dst, per edge type (indices identical across layers)
  hist_kernel<<<(2*E_EDGES + 255)/256, 256, 0, stream>>>(same, diff, DEG);
  scan_kernel<<<2, 1024, 0, stream>>>(DEG, RP0, RP1, NX0, NX1);
  {
    const long nchunk = (2L*E_EDGES + SC_CHUNK - 1) / SC_CHUNK;
    scatter_kernel<<<(int)(nchunk*8), 256, 0, stream>>>(same, diff, NX0, NX1, ADJ0, ADJ1);
  }

  for (int l = 0; l < 4; l++) {
    if (l == 0)
      gemm0_mfma<<<(N_NODES + 127)/128, 512, 0, stream>>>(feat, B0bf, BIAS0, QS, KV0, KV1);
    else
      proj_small_kernel<<<(N_NODES + 15)/16, 256, 0, stream>>>(
          XPRE4 + (size_t)(l-1)*N_NODES*D, BNP + (l-1)*(NBNP*40),
          gamma + (l-1)*D, beta + (l-1)*D,
          WL + (size_t)(l-1)*3200, BIASL + (size_t)(l-1)*160, QS, KV0, KV1);

    attn_fused<<<N_NODES/4, 256, 0, stream>>>(
        RP0, ADJ0, RP1, ADJ1, QS, KV0, KV1, w1, w2, l,
        XPRE4 + (size_t)l*N_NODES*D, BNP + l*(NBNP*40));
  }

  final_kernel<<<(N_NODES + 255)/256, 256, 0, stream>>>(
      XPRE4, BNP, gamma, beta, Wout, bout, (float*)d_out);
}

// Round 8
// 977.090 us; speedup vs baseline: 1.1673x; 1.0100x over previous
//
#include <hip/hip_runtime.h>
#include <math.h>

#define N_NODES 50000
#define E_EDGES 1600000
#define F_IN    2000
#define D       20
#define NCOL    160   // 2 edge types * [q s k v] * 20
#define KPAD    2016  // 63 * 32
#define NBNP    64    // BN partial slots

#define INV_SQRT_D 0.22360679774997896f

typedef __bf16 bf16x8 __attribute__((ext_vector_type(8)));
typedef __bf16 bf16x4 __attribute__((ext_vector_type(4)));
typedef float  f32x4  __attribute__((ext_vector_type(4)));

// Output routing: col -> QS[node][et*40 + mat*20 + d] (mat 0=q,1=s)
//                     -> KV[et][node*64 + (mat-2)*20 + d] (mat 2=k,3=v; 128B rows)

// ---------------- pack weights + zero accumulators --------------------------------------
__global__ void pack_kernel(
    const float* __restrict__ W0q, const float* __restrict__ W0k,
    const float* __restrict__ W0v, const float* __restrict__ W0s,
    const float* __restrict__ b0q, const float* __restrict__ b0k,
    const float* __restrict__ b0v, const float* __restrict__ b0s,
    const float* __restrict__ Wq,  const float* __restrict__ Wk,
    const float* __restrict__ Wv,  const float* __restrict__ Ws_,
    const float* __restrict__ bq,  const float* __restrict__ bk,
    const float* __restrict__ bv,  const float* __restrict__ bs_,
    __bf16* __restrict__ B0, float* __restrict__ bias0,
    float* __restrict__ WL, float* __restrict__ biasL,
    float* __restrict__ bnp, int* __restrict__ deg)
{
  long idx = (long)blockIdx.x * blockDim.x + threadIdx.x;
  if (idx < (long)NCOL*KPAD) {              // B0T: [160][2016] bf16
    int col = (int)(idx / KPAD), k = (int)(idx % KPAD);
    int et = col / 80, r = col % 80, mat = r / 20, d = r % 20;
    const float* w = (mat==0)?W0q:(mat==1)?W0s:(mat==2)?W0k:W0v;
    float v = (k < F_IN) ? w[((size_t)et*F_IN + k)*D + d] : 0.f;
    B0[idx] = (__bf16)v;
    return;
  }
  idx -= (long)NCOL*KPAD;
  if (idx < 160) {                          // bias0
    int col = (int)idx;
    int et = col / 80, r = col % 80, mat = r / 20, d = r % 20;
    const float* b = (mat==0)?b0q:(mat==1)?b0s:(mat==2)?b0k:b0v;
    bias0[col] = b[et*D + d];
    return;
  }
  idx -= 160;
  if (idx < 9600) {                         // WL: 3 x [20][160]
    int l = (int)(idx / 3200), rem = (int)(idx % 3200);
    int k = rem / NCOL, col = rem % NCOL;
    int et = col / 80, r = col % 80, mat = r / 20, d = r % 20;
    const float* w = (mat==0)?Wq:(mat==1)?Ws_:(mat==2)?Wk:Wv;
    WL[idx] = w[(((size_t)l*2 + et)*D + k)*D + d];
    return;
  }
  idx -= 9600;
  if (idx < 480) {                          // biasL: 3 x [160]
    int l = (int)(idx / NCOL), col = (int)(idx % NCOL);
    int et = col / 80, r = col % 80, mat = r / 20, d = r % 20;
    const float* b = (mat==0)?bq:(mat==1)?bs_:(mat==2)?bk:bv;
    biasL[idx] = b[(l*2 + et)*D + d];
    return;
  }
  idx -= 480;
  if (idx < 4*NBNP*40) { bnp[idx] = 0.f; return; } // BN partials: [4][64][40]
  idx -= 4*NBNP*40;
  if (idx < 2*N_NODES) { deg[idx] = 0; return; }
}

// ---------------- CSR build (XCD-partitioned: counter/adj lines stay in one L2) ---------
#define SC_EPT 16
#define SC_CHUNK (256*SC_EPT)

__global__ void hist_kernel(const int* __restrict__ same, const int* __restrict__ diff,
                            int* __restrict__ deg)
{
  const int part  = blockIdx.x & 7;
  const int chunk = blockIdx.x >> 3;
  const int lo = part * (N_NODES/8);
  const int hi = lo + (N_NODES/8);
  const long i0 = (long)chunk * SC_CHUNK + threadIdx.x;
#pragma unroll
  for (int it = 0; it < SC_EPT; ++it) {
    long i = i0 + (long)it*256;
    if (i >= 2L*E_EDGES) break;
    int et = (i >= E_EDGES) ? 1 : 0;
    long e = i - (long)et*E_EDGES;
    const int* ix = et ? diff : same;
    int dst = ix[E_EDGES + e];
    if (dst >= lo && dst < hi)
      atomicAdd(&deg[(size_t)et*N_NODES + dst], 1);
  }
}

__global__ void scan_kernel(const int* __restrict__ deg,
                            int* __restrict__ rowptr0, int* __restrict__ rowptr1,
                            int* __restrict__ next0, int* __restrict__ next1)
{
  const int et = blockIdx.x;
  const int* dg = deg + (size_t)et*N_NODES;
  int* rp = et ? rowptr1 : rowptr0;
  int* np = et ? next1 : next0;
  __shared__ int part[1024];
  const int t = threadIdx.x;
  const int per = (N_NODES + 1023) / 1024;  // 49
  const int b = t * per;
  const int e = (b + per < N_NODES) ? (b + per) : N_NODES;
  int s = 0;
  for (int i = b; i < e; i++) s += dg[i];
  part[t] = s;
  __syncthreads();
  for (int o = 1; o < 1024; o <<= 1) {
    int v = (t >= o) ? part[t-o] : 0;
    __syncthreads();
    part[t] += v;
    __syncthreads();
  }
  int run = (t == 0) ? 0 : part[t-1];
  for (int i = b; i < e; i++) {
    rp[i] = run; np[i] = run;
    run += dg[i];
  }
  if (t == 0) rp[N_NODES] = part[1023];
}

__global__ void scatter_kernel(const int* __restrict__ same, const int* __restrict__ diff,
                               int* __restrict__ next0, int* __restrict__ next1,
                               int* __restrict__ adj0, int* __restrict__ adj1)
{
  const int part  = blockIdx.x & 7;
  const int chunk = blockIdx.x >> 3;
  const int lo = part * (N_NODES/8);
  const int hi = lo + (N_NODES/8);
  const long i0 = (long)chunk * SC_CHUNK + threadIdx.x;
#pragma unroll
  for (int it = 0; it < SC_EPT; ++it) {
    long i = i0 + (long)it*256;
    if (i >= 2L*E_EDGES) break;
    int et = (i >= E_EDGES) ? 1 : 0;
    long e = i - (long)et*E_EDGES;
    const int* ix = et ? diff : same;
    int dst = ix[E_EDGES + e];
    if (dst >= lo && dst < hi) {
      int src = ix[e];
      int* np  = et ? next1 : next0;
      int* adj = et ? adj1  : adj0;
      int pos = atomicAdd(&np[dst], 1);
      adj[pos] = src;
    }
  }
}

// ---------------- layer-0 MFMA GEMM: 64-row tiles, 256 threads, 782 blocks --------------
__launch_bounds__(256)
__global__ void gemm0_mfma(const float* __restrict__ A,
                           const __bf16* __restrict__ Bt,
                           const float* __restrict__ bias,
                           __bf16* __restrict__ QS,
                           __bf16* __restrict__ KV0, __bf16* __restrict__ KV1)
{
  __shared__ __bf16 as[64*32];
  const int t    = threadIdx.x;
  const int lane = t & 63;
  const int wid  = t >> 6;          // 0..3
  const int wr   = wid >> 1;        // 0..1 -> rows wr*32
  const int wc   = wid & 1;         // 0..1 -> cols wc*80
  const int rb0  = blockIdx.x * 64;

  const int srow = t >> 2;          // staging: row 0..63
  const int skc  = (t & 3) * 8;     // k chunk of 8
  const int arow = rb0 + srow;
  const float* aptr = A + (size_t)arow * F_IN;

  const int lrow = lane & 15;       // frag row/col within 16
  const int lkb  = (lane >> 4) * 8; // k sub-block

  f32x4 acc[2][5];
#pragma unroll
  for (int i = 0; i < 2; i++)
#pragma unroll
    for (int j = 0; j < 5; j++) acc[i][j] = (f32x4){0.f,0.f,0.f,0.f};

  float4 p0, p1;
  auto loadA = [&](int k0) {
    int k = k0 + skc;
    if (arow < N_NODES) {
      if (k + 8 <= F_IN) {
        p0 = *(const float4*)(aptr + k);
        p1 = *(const float4*)(aptr + k + 4);
      } else {
        float tmp[8];
#pragma unroll
        for (int i = 0; i < 8; i++) tmp[i] = (k + i < F_IN) ? aptr[k + i] : 0.f;
        p0 = make_float4(tmp[0],tmp[1],tmp[2],tmp[3]);
        p1 = make_float4(tmp[4],tmp[5],tmp[6],tmp[7]);
      }
    } else {
      p0 = make_float4(0,0,0,0); p1 = p0;
    }
  };

  loadA(0);
  for (int s = 0; s < 63; s++) {
    bf16x8 h;
    h[0]=(__bf16)p0.x; h[1]=(__bf16)p0.y; h[2]=(__bf16)p0.z; h[3]=(__bf16)p0.w;
    h[4]=(__bf16)p1.x; h[5]=(__bf16)p1.y; h[6]=(__bf16)p1.z; h[7]=(__bf16)p1.w;
    *(bf16x8*)&as[srow*32 + skc] = h;
    __syncthreads();
    if (s + 1 < 63) loadA((s + 1) * 32);

    bf16x8 af[2];
#pragma unroll
    for (int rf = 0; rf < 2; rf++)
      af[rf] = *(bf16x8*)&as[(wr*32 + rf*16 + lrow)*32 + lkb];
    bf16x8 bfr[5];
#pragma unroll
    for (int cf = 0; cf < 5; cf++)
      bfr[cf] = *(const bf16x8*)(Bt + (size_t)(wc*80 + cf*16 + lrow)*KPAD + s*32 + lkb);
#pragma unroll
    for (int rf = 0; rf < 2; rf++)
#pragma unroll
      for (int cf = 0; cf < 5; cf++)
        acc[rf][cf] = __builtin_amdgcn_mfma_f32_16x16x32_bf16(af[rf], bfr[cf], acc[rf][cf], 0, 0, 0);
    __syncthreads();
  }

  // epilogue: C/D layout col=lane&15, row=(lane>>4)*4 + j ; route to QS/KV
#pragma unroll
  for (int rf = 0; rf < 2; rf++) {
#pragma unroll
    for (int cf = 0; cf < 5; cf++) {
      int col = wc*80 + cf*16 + lrow;
      int et = col / 80, r = col % 80, mat = r / 20, d = r % 20;
      float bv = bias[col];
      __bf16* kvp = et ? KV1 : KV0;
#pragma unroll
      for (int j = 0; j < 4; j++) {
        int row = rb0 + wr*32 + rf*16 + (lane >> 4)*4 + j;
        if (row < N_NODES) {
          __bf16 val = (__bf16)(acc[rf][cf][j] + bv);
          if (mat < 2) QS[(size_t)row*80 + et*40 + mat*20 + d] = val;
          else         kvp[(size_t)row*64 + (mat-2)*20 + d]   = val;
        }
      }
    }
  }
}

// ---------------- layers 1..3 projection with inline BN+leakyReLU -----------------------
__launch_bounds__(256)
__global__ void proj_small_kernel(const float* __restrict__ xp, const float* __restrict__ bnl,
                                  const float* __restrict__ gam, const float* __restrict__ bet,
                                  const float* __restrict__ W, const float* __restrict__ bias,
                                  __bf16* __restrict__ QS,
                                  __bf16* __restrict__ KV0, __bf16* __restrict__ KV1)
{
  __shared__ float ws[20*160];
  __shared__ float xs[16*20];
  __shared__ float Ac[20], Bc[20];
  const int t = threadIdx.x;
  const int n0 = blockIdx.x * 16;
#pragma unroll
  for (int i = 0; i < 13; i++) {
    int idx = t + i*256;
    if (idx < 3200) ws[idx] = W[idx];
  }
  if (t < 20) {
    float s1 = 0.f, s2 = 0.f;
    for (int s = 0; s < NBNP; s++) { s1 += bnl[s*40 + t]; s2 += bnl[s*40 + 20 + t]; }
    float mu  = s1 * (1.f/N_NODES);
    float var = s2 * (1.f/N_NODES) - mu*mu;
    float a = rsqrtf(var + 1e-5f) * gam[t];
    Ac[t] = a; Bc[t] = bet[t] - mu*a;
  }
  __syncthreads();
#pragma unroll
  for (int i = 0; i < 2; i++) {
    int idx = t + i*256;
    if (idx < 320) {
      int nl = idx / 20, k = idx % 20;
      int n = n0 + nl;
      float x = (n < N_NODES) ? xp[(size_t)n*D + k] : 0.f;
      float y = x*Ac[k] + Bc[k];
      xs[idx] = (y > 0.f) ? y : 0.01f*y;
    }
  }
  __syncthreads();
#pragma unroll
  for (int i = 0; i < 10; i++) {
    int idx = t + i*256;
    int nl = idx / NCOL, col = idx % NCOL;
    int n = n0 + nl;
    if (n < N_NODES) {
      float acc = bias[col];
#pragma unroll
      for (int k = 0; k < 20; k++) acc += xs[nl*20 + k] * ws[k*NCOL + col];
      int et = col / 80, r = col % 80, mat = r / 20, d = r % 20;
      __bf16 val = (__bf16)acc;
      if (mat < 2) QS[(size_t)n*80 + et*40 + mat*20 + d] = val;
      else         (et ? KV1 : KV0)[(size_t)n*64 + (mat-2)*20 + d] = val;
    }
  }
}

// ---------------- fused attention + combine + BN partial sums ---------------------------
// ONE WAVE PER NODE: lanes 0-31 et0, lanes 32-63 et1. Paired-edge gather (2 lines in
// flight per lane). No block-level sync: per-wave BN atomics via cndmask lane-select.
__launch_bounds__(256)
__global__ void attn_fused(const int* __restrict__ rp0, const int* __restrict__ adj0,
                           const int* __restrict__ rp1, const int* __restrict__ adj1,
                           const __bf16* __restrict__ QS,
                           const __bf16* __restrict__ KV0, const __bf16* __restrict__ KV1,
                           const float* __restrict__ w1, const float* __restrict__ w2, int l,
                           float* __restrict__ xpre, float* __restrict__ bnp)
{
  const int t    = threadIdx.x;
  const int wv   = t >> 6;
  const int lane = t & 63;
  const int half = lane >> 5;         // edge type
  const int sl   = lane & 31;
  const int node = blockIdx.x*4 + wv; // grid = 12500 exactly

  const int* rowptr = half ? rp1 : rp0;
  const int* adj    = half ? adj1 : adj0;
  const __bf16* kvb = half ? KV1 : KV0;
  const __bf16* rq  = QS + (size_t)node*80 + half*40;   // q[0..20) s[20..40)

  float qf[20];
  {
    bf16x8 q0 = *(const bf16x8*)(rq);
    bf16x8 q1 = *(const bf16x8*)(rq + 8);
    bf16x4 q2 = *(const bf16x4*)(rq + 16);
#pragma unroll
    for (int i = 0; i < 8; i++) { qf[i] = (float)q0[i]; qf[8+i] = (float)q1[i]; }
#pragma unroll
    for (int i = 0; i < 4; i++) qf[16+i] = (float)q2[i];
  }

  const int beg = rowptr[node], end = rowptr[node+1];
  float z = 0.f;
  float S[20];
#pragma unroll
  for (int d = 0; d < 20; d++) S[d] = 0.f;

  int i = beg + sl;
  // paired loop: 2 edges (2 cache lines) in flight per lane
  for (; i + 32 < end; i += 64) {
    const int s0 = adj[i], s1 = adj[i+32];
    const __bf16* kva = kvb + (size_t)s0*64;
    const __bf16* kvc = kvb + (size_t)s1*64;
    bf16x8 a0 = *(const bf16x8*)(kva);
    bf16x8 a1 = *(const bf16x8*)(kva + 8);
    bf16x8 a2 = *(const bf16x8*)(kva + 16);
    bf16x8 a3 = *(const bf16x8*)(kva + 24);
    bf16x8 a4 = *(const bf16x8*)(kva + 32);
    bf16x8 b0 = *(const bf16x8*)(kvc);
    bf16x8 b1 = *(const bf16x8*)(kvc + 8);
    bf16x8 b2 = *(const bf16x8*)(kvc + 16);
    bf16x8 b3 = *(const bf16x8*)(kvc + 24);
    bf16x8 b4 = *(const bf16x8*)(kvc + 32);

    float d0 = 0.f, d1 = 0.f;
#pragma unroll
    for (int j = 0; j < 8; j++) { d0 += qf[j]*(float)a0[j];     d1 += qf[j]*(float)b0[j]; }
#pragma unroll
    for (int j = 0; j < 8; j++) { d0 += qf[8+j]*(float)a1[j];   d1 += qf[8+j]*(float)b1[j]; }
#pragma unroll
    for (int j = 0; j < 4; j++) { d0 += qf[16+j]*(float)a2[j];  d1 += qf[16+j]*(float)b2[j]; }
    const float w0 = __expf(fminf(d0*INV_SQRT_D, 80.f));
    const float w1v= __expf(fminf(d1*INV_SQRT_D, 80.f));
    z += w0 + w1v;
#pragma unroll
    for (int d = 0; d < 4; d++) S[d]     += w0*(float)a2[4+d] + w1v*(float)b2[4+d];
#pragma unroll
    for (int d = 0; d < 8; d++) S[4+d]   += w0*(float)a3[d]   + w1v*(float)b3[d];
#pragma unroll
    for (int d = 0; d < 8; d++) S[12+d]  += w0*(float)a4[d]   + w1v*(float)b4[d];
  }
  // tail: at most one edge per lane remains
  if (i < end) {
    const int s0 = adj[i];
    const __bf16* kva = kvb + (size_t)s0*64;
    bf16x8 a0 = *(const bf16x8*)(kva);
    bf16x8 a1 = *(const bf16x8*)(kva + 8);
    bf16x8 a2 = *(const bf16x8*)(kva + 16);
    bf16x8 a3 = *(const bf16x8*)(kva + 24);
    bf16x8 a4 = *(const bf16x8*)(kva + 32);
    float d0 = 0.f;
#pragma unroll
    for (int j = 0; j < 8; j++) d0 += qf[j]     * (float)a0[j];
#pragma unroll
    for (int j = 0; j < 8; j++) d0 += qf[8 + j] * (float)a1[j];
#pragma unroll
    for (int j = 0; j < 4; j++) d0 += qf[16 + j]* (float)a2[j];
    const float w0 = __expf(fminf(d0*INV_SQRT_D, 80.f));
    z += w0;
#pragma unroll
    for (int d = 0; d < 4; d++) S[d]     += w0*(float)a2[4+d];
#pragma unroll
    for (int d = 0; d < 8; d++) S[4+d]   += w0*(float)a3[d];
#pragma unroll
    for (int d = 0; d < 8; d++) S[12+d]  += w0*(float)a4[d];
  }

  // butterfly sum within each 32-lane half
#pragma unroll
  for (int o = 16; o >= 1; o >>= 1) {
    z += __shfl_xor(z, o, 64);
#pragma unroll
    for (int d = 0; d < 20; d++) S[d] += __shfl_xor(S[d], o, 64);
  }

  // per-et output: S/z + skip (s at rq+20)
  const float inv = (z > 0.f) ? 1.f/z : 0.f;
  float outv[20];
  {
    bf16x4 s0 = *(const bf16x4*)(rq + 20);
    bf16x8 s1 = *(const bf16x8*)(rq + 24);
    bf16x8 s2 = *(const bf16x8*)(rq + 32);
#pragma unroll
    for (int i2 = 0; i2 < 4; i2++) outv[i2] = S[i2]*inv + (float)s0[i2];
#pragma unroll
    for (int i2 = 0; i2 < 8; i2++) { outv[4+i2]  = S[4+i2]*inv  + (float)s1[i2];
                                     outv[12+i2] = S[12+i2]*inv + (float)s2[i2]; }
  }

  // cross-half combine (all 64 lanes end with x)
  const float wa = w1[l], wb = w2[l];
  const float c0 = wa/(wa+wb), c1 = wb/(wa+wb);
  const float cme = half ? c1 : c0;
  const float cot = half ? c0 : c1;
  float x[20];
#pragma unroll
  for (int d = 0; d < 20; d++) {
    float o2 = __shfl_xor(outv[d], 32, 64);
    x[d] = cme*outv[d] + cot*o2;
  }

  if (lane == 0) {
    float* xo = xpre + (size_t)node*D;
#pragma unroll
    for (int j = 0; j < 5; j++) {
      float4 o4 = make_float4(x[4*j], x[4*j+1], x[4*j+2], x[4*j+3]);
      *(float4*)(xo + 4*j) = o4;
    }
  }

  // per-wave BN atomics: lane sl holds x[sl] via unrolled select (no scratch)
  float v = x[0];
#pragma unroll
  for (int d = 1; d < 20; d++) v = (sl == d) ? x[d] : v;
  if (sl < 20) {
    float* slot = bnp + (size_t)((blockIdx.x*4 + wv) & (NBNP-1))*40;
    if (half == 0) atomicAdd(&slot[sl], v);
    else           atomicAdd(&slot[20 + sl], v*v);
  }
}

// ---------------- final: BN+lrelu (inline) on 4 layers, concat @ Wout + bout ------------
__launch_bounds__(256)
__global__ void final_kernel(const float* __restrict__ xpre4, const float* __restrict__ bnp,
                             const float* __restrict__ gam, const float* __restrict__ bet,
                             const float* __restrict__ Wout, const float* __restrict__ bout,
                             float* __restrict__ out)
{
  __shared__ float Ac[80], Bc[80], wlds[160];
  const int t = threadIdx.x;
  if (t < 80) {
    int l = t / 20, d = t % 20;
    const float* b = bnp + l*(NBNP*40);
    float s1 = 0.f, s2 = 0.f;
    for (int s = 0; s < NBNP; s++) { s1 += b[s*40 + d]; s2 += b[s*40 + 20 + d]; }
    float mu  = s1 * (1.f/N_NODES);
    float var = s2 * (1.f/N_NODES) - mu*mu;
    float a = rsqrtf(var + 1e-5f) * gam[t];
    Ac[t] = a; Bc[t] = bet[t] - mu*a;
  }
  if (t < 160) wlds[t] = Wout[t];
  __syncthreads();

  const int n = blockIdx.x*256 + t;
  if (n >= N_NODES) return;
  float a0 = bout[0], a1 = bout[1];
#pragma unroll
  for (int l = 0; l < 4; l++) {
    const float* base = xpre4 + (size_t)l*N_NODES*D + (size_t)n*D;
#pragma unroll
    for (int d = 0; d < D; d++) {
      int idx = l*20 + d;
      float y = base[d]*Ac[idx] + Bc[idx];
      y = (y > 0.f) ? y : 0.01f*y;
      a0 += y * wlds[idx*2 + 0];
      a1 += y * wlds[idx*2 + 1];
    }
  }
  out[n*2+0] = a0;
  out[n*2+1] = a1;
}

// ----------------------------------------------------------------------------------------
extern "C" void kernel_launch(void* const* d_in, const int* in_sizes, int n_in,
                              void* d_out, int out_size, void* d_ws, size_t ws_size,
                              hipStream_t stream)
{
  const float* feat = (const float*)d_in[0];
  const int*   same = (const int*)d_in[1];
  const int*   diff = (const int*)d_in[2];
  const float* W0q = (const float*)d_in[3];
  const float* b0q = (const float*)d_in[4];
  const float* W0k = (const float*)d_in[5];
  const float* b0k = (const float*)d_in[6];
  const float* W0v = (const float*)d_in[7];
  const float* b0v = (const float*)d_in[8];
  const float* W0s = (const float*)d_in[9];
  const float* b0s = (const float*)d_in[10];
  const float* Wq  = (const float*)d_in[11];
  const float* bq  = (const float*)d_in[12];
  const float* Wk  = (const float*)d_in[13];
  const float* bk  = (const float*)d_in[14];
  const float* Wv  = (const float*)d_in[15];
  const float* bv  = (const float*)d_in[16];
  const float* Ws_ = (const float*)d_in[17];
  const float* bs_ = (const float*)d_in[18];
  const float* w1  = (const float*)d_in[19];
  const float* w2  = (const float*)d_in[20];
  const float* gamma = (const float*)d_in[21];
  const float* beta  = (const float*)d_in[22];
  const float* Wout  = (const float*)d_in[23];
  const float* bout  = (const float*)d_in[24];

  float* wsf  = (float*)d_ws;
  __bf16*  QS    = (__bf16*)wsf;                 // 4,000,000 bf16 = 2,000,000 f [N][80]
  __bf16*  KV0   = (__bf16*)(wsf + 2000000);     // 3,200,000 bf16 rows of 64 (128B aligned)
  __bf16*  KV1   = (__bf16*)(wsf + 3600000);
  float*   XPRE4 = wsf + 5200000;                // 4,000,000  [4][N][20] pre-BN
  __bf16*  B0bf  = (__bf16*)(wsf + 9200000);     //   322,560 bf16 = 161,280 f
  float*   BIAS0 = wsf + 9361280;                //       160
  float*   WL    = wsf + 9361440;                //     9,600  3x[20][160]
  float*   BIASL = wsf + 9371040;                //       480
  float*   BNP   = wsf + 9371520;                //    10,240  [4][64][40]
  int*     ib    = (int*)(wsf + 9381760);
  int* DEG  = ib;                                // 100,000  [2][N]
  int* RP0  = ib + 100000;                       //  50,004
  int* RP1  = ib + 150004;                       //  50,004
  int* NX0  = ib + 200008;                       //  50,000
  int* NX1  = ib + 250008;                       //  50,000
  int* ADJ0 = ib + 300008;                       // 1,600,000
  int* ADJ1 = ib + 1900008;                      // 1,600,000

  // pack weights + zero BN partials/degrees
  const int packN = NCOL*KPAD + 160 + 9600 + 480 + 4*NBNP*40 + 2*N_NODES;  // 443,040
  pack_kernel<<<(packN + 255)/256, 256, 0, stream>>>(
      W0q, W0k, W0v, W0s, b0q, b0k, b0v, b0s,
      Wq, Wk, Wv, Ws_, bq, bk, bv, bs_,
      B0bf, BIAS0, WL, BIASL, BNP, DEG);

  // CSR by dst, per edge type (indices identical across layers)
  const long nchunk = (2L*E_EDGES + SC_CHUNK - 1) / SC_CHUNK;
  hist_kernel<<<(int)(nchunk*8), 256, 0, stream>>>(same, diff, DEG);
  scan_kernel<<<2, 1024, 0, stream>>>(DEG, RP0, RP1, NX0, NX1);
  scatter_kernel<<<(int)(nchunk*8), 256, 0, stream>>>(same, diff, NX0, NX1, ADJ0, ADJ1);

  for (int l = 0; l < 4; l++) {
    if (l == 0)
      gemm0_mfma<<<(N_NODES + 63)/64, 256, 0, stream>>>(feat, B0bf, BIAS0, QS, KV0, KV1);
    else
      proj_small_kernel<<<(N_NODES + 15)/16, 256, 0, stream>>>(
          XPRE4 + (size_t)(l-1)*N_NODES*D, BNP + (l-1)*(NBNP*40),
          gamma + (l-1)*D, beta + (l-1)*D,
          WL + (size_t)(l-1)*3200, BIASL + (size_t)(l-1)*160, QS, KV0, KV1);

    attn_fused<<<N_NODES/4, 256, 0, stream>>>(
        RP0, ADJ0, RP1, ADJ1, QS, KV0, KV1, w1, w2, l,
        XPRE4 + (size_t)l*N_NODES*D, BNP + l*(NBNP*40));
  }

  final_kernel<<<(N_NODES + 255)/256, 256, 0, stream>>>(
      XPRE4, BNP, gamma, beta, Wout, bout, (float*)d_out);
}